// Round 8
// baseline (147.860 us; speedup 1.0000x reference)
//
#include <hip/hip_runtime.h>
#include <hip/hip_bf16.h>

#define TT   2048   // B*S tokens
#define HH   2048   // hidden dim
#define SEQ  1024
#define NHQ  16
#define NKVH 8
#define HDD  128

typedef __attribute__((ext_vector_type(8))) short short8;
typedef __attribute__((ext_vector_type(4))) float f32x4;
typedef __attribute__((ext_vector_type(4))) int int4v;
typedef _Float16 half8 __attribute__((ext_vector_type(8)));

static __device__ __forceinline__ unsigned short f2h(float f) {
  union { _Float16 h; unsigned short u; } c;
  c.h = (_Float16)f;
  return c.u;
}
static __device__ __forceinline__ half8 s2h(short8 v) {
  union { short8 s; half8 h; } c;
  c.s = v;
  return c.h;
}

#define GLD_LDS16(gp, lp)                                                        \
  __builtin_amdgcn_global_load_lds(                                              \
      (const __attribute__((address_space(1))) void*)(const void*)(gp),          \
      (__attribute__((address_space(3))) void*)(void*)(lp), 16, 0, 0)

// ---------------------------------------------------------------------------
// K1: per-row act_quant -> int8 (vectorized float4 loads, shfl reduce)
// ---------------------------------------------------------------------------
__global__ __launch_bounds__(256) void k_actquant(const float* __restrict__ x,
                                                  signed char* __restrict__ xq,
                                                  float* __restrict__ as_inv) {
  int row = blockIdx.x, tid = threadIdx.x;
  int wave = tid >> 6, lane = tid & 63;
  const float4* xr4 = (const float4*)(x + (size_t)row * HH);
  float4 a = xr4[tid * 2], b = xr4[tid * 2 + 1];
  float am = fmaxf(fmaxf(fmaxf(fabsf(a.x), fabsf(a.y)), fmaxf(fabsf(a.z), fabsf(a.w))),
                   fmaxf(fmaxf(fabsf(b.x), fabsf(b.y)), fmaxf(fabsf(b.z), fabsf(b.w))));
#pragma unroll
  for (int o = 32; o; o >>= 1) am = fmaxf(am, __shfl_xor(am, o));
  __shared__ float wred[4];
  if (lane == 0) wred[wave] = am;
  __syncthreads();
  am = fmaxf(fmaxf(wred[0], wred[1]), fmaxf(wred[2], wred[3]));
  am = fmaxf(am, 1e-5f);
  if (tid == 0) as_inv[row] = am / 127.f;
  float scale = 127.f / am;
  float vals[8] = {a.x, a.y, a.z, a.w, b.x, b.y, b.z, b.w};
  unsigned int u0 = 0, u1 = 0;
#pragma unroll
  for (int j = 0; j < 4; ++j) {
    int q = (int)fminf(fmaxf(rintf(vals[j] * scale), -128.f), 127.f);
    u0 |= (unsigned int)(q & 255) << (8 * j);
  }
#pragma unroll
  for (int j = 0; j < 4; ++j) {
    int q = (int)fminf(fmaxf(rintf(vals[4 + j] * scale), -128.f), 127.f);
    u1 |= (unsigned int)(q & 255) << (8 * j);
  }
  uint2 uu; uu.x = u0; uu.y = u1;
  ((uint2*)(xq + (size_t)row * HH))[tid] = uu;
}

// ---------------------------------------------------------------------------
// K2: deterministic partial |w| sums (f64), all 4 weights in one dispatch
// ---------------------------------------------------------------------------
__global__ __launch_bounds__(256) void k_absum_all(const float* __restrict__ wq,
                                                   const float* __restrict__ wk,
                                                   const float* __restrict__ wv,
                                                   const float* __restrict__ wo,
                                                   double* __restrict__ part) {
  int wid = blockIdx.y;
  const float* w = (wid == 0) ? wq : (wid == 1) ? wk : (wid == 2) ? wv : wo;
  int nq = ((wid == 0 || wid == 3) ? 4194304 : 2097152) >> 2;
  double s = 0.0;
  for (int i = blockIdx.x * 256 + threadIdx.x; i < nq; i += 256 * 256) {
    float4 v = ((const float4*)w)[i];
    s += (double)fabsf(v.x) + (double)fabsf(v.y) + (double)fabsf(v.z) + (double)fabsf(v.w);
  }
  __shared__ double red[256];
  red[threadIdx.x] = s;
  __syncthreads();
  for (int st = 128; st > 0; st >>= 1) {
    if (threadIdx.x < st) red[threadIdx.x] += red[threadIdx.x + st];
    __syncthreads();
  }
  if (threadIdx.x == 0) part[wid * 256 + blockIdx.x] = red[0];
}

__global__ __launch_bounds__(256) void k_wscale(const double* __restrict__ part,
                                                float* __restrict__ wsc) {
  __shared__ double red[256];
  const double nvals[4] = {4194304.0, 2097152.0, 2097152.0, 4194304.0};
  for (int w = 0; w < 4; ++w) {
    red[threadIdx.x] = part[w * 256 + threadIdx.x];
    __syncthreads();
    for (int st = 128; st > 0; st >>= 1) {
      if (threadIdx.x < st) red[threadIdx.x] += red[threadIdx.x + st];
      __syncthreads();
    }
    if (threadIdx.x == 0) {
      float mean = (float)(red[0] / nvals[w]);
      wsc[w] = fmaxf(mean, 1e-5f);
    }
    __syncthreads();
  }
}

// ---------------------------------------------------------------------------
// K3: ternary weight quant -> int8, all 4 weights in one dispatch
// ---------------------------------------------------------------------------
__global__ __launch_bounds__(256) void k_wquant_all(const float* __restrict__ wq,
                                                    const float* __restrict__ wk,
                                                    const float* __restrict__ wv,
                                                    const float* __restrict__ wo,
                                                    signed char* __restrict__ wqk,
                                                    signed char* __restrict__ wvt,
                                                    signed char* __restrict__ wot,
                                                    const float* __restrict__ wsc) {
  const int NQ = 3145728;
  for (int qi = blockIdx.x * 256 + threadIdx.x; qi < NQ; qi += gridDim.x * 256) {
    const float* src; signed char* dst; float inv; int off;
    if (qi < 1048576)      { src = wq; dst = wqk;           off = qi;           inv = 1.f / wsc[0]; }
    else if (qi < 1572864) { src = wk; dst = wqk + 4194304; off = qi - 1048576; inv = 1.f / wsc[1]; }
    else if (qi < 2097152) { src = wv; dst = wvt;           off = qi - 1572864; inv = 1.f / wsc[2]; }
    else                   { src = wo; dst = wot;           off = qi - 2097152; inv = 1.f / wsc[3]; }
    float4 v = ((const float4*)src)[off];
    unsigned int u = 0;
    float vv[4] = {v.x, v.y, v.z, v.w};
#pragma unroll
    for (int j = 0; j < 4; ++j) {
      int q = (int)fminf(fmaxf(rintf(vv[j] * inv), -1.f), 1.f);
      u |= (unsigned int)(q & 255) << (8 * j);
    }
    ((unsigned int*)dst)[off] = u;
  }
}

// ---------------------------------------------------------------------------
// K4: i8 MFMA NT-GEMM, 128x128 tile, BK=64, global_load_lds staging,
// source-side XOR swizzle. (unchanged from round 7)
// ---------------------------------------------------------------------------
__global__ __launch_bounds__(256) void k_gemm_i8(const signed char* __restrict__ A0,
                                                 const signed char* __restrict__ B0,
                                                 const signed char* __restrict__ B1,
                                                 int which,
                                                 float* __restrict__ d0,
                                                 unsigned short* __restrict__ dh,
                                                 const float* __restrict__ asx,
                                                 const float* __restrict__ wsc,
                                                 const float* __restrict__ qn,
                                                 const float* __restrict__ kn,
                                                 const float* __restrict__ cs,
                                                 const float* __restrict__ sn,
                                                 unsigned short* __restrict__ qf,
                                                 unsigned short* __restrict__ kf) {
  const int K = HH;
  __shared__ signed char As[8192];   // [128][64] (source-swizzled within rows)
  __shared__ signed char Bs[8192];
  int tid = threadIdx.x;
  int wave = tid >> 6, lane = tid & 63, l15 = lane & 15, g = lane >> 4;
  int wm = wave >> 1, wn = wave & 1;

  const signed char *Ap, *Bp;
  int bm, bn, mode;
  if (which == 0) {
    int gid = (blockIdx.x & 7) * 64 + (blockIdx.x >> 3);   // XCD chunk, 512 blocks
    if (gid < 384) { mode = 0; bm = (gid / 24) * 128; bn = (gid % 24) * 128; Ap = A0; Bp = B0; }
    else { mode = 1; int vid = gid - 384; bm = (vid >> 4) * 128; bn = (vid & 15) * 128; Ap = B1; Bp = A0; }
  } else {
    int gid = (blockIdx.x & 7) * 32 + (blockIdx.x >> 3);   // 256 blocks
    mode = 2; bm = (gid >> 4) * 128; bn = (gid & 15) * 128; Ap = A0; Bp = B0;
  }

  int4v acc[4][4] = {};
  for (int k0 = 0; k0 < K; k0 += 64) {
    __syncthreads();
#pragma unroll
    for (int r = 0; r < 2; ++r) {
      int c = r * 256 + tid;
      int row = c >> 2;
      int kk = ((c & 3) << 4) ^ ((row & 3) << 4);
      GLD_LDS16(Ap + (size_t)(bm + row) * K + k0 + kk, As + c * 16);
      GLD_LDS16(Bp + (size_t)(bn + row) * K + k0 + kk, Bs + c * 16);
    }
    __syncthreads();
    int4v af[4], bf[4];
#pragma unroll
    for (int i = 0; i < 4; ++i) {
      int ra = wm * 64 + i * 16 + l15;
      af[i] = *(const int4v*)&As[ra * 64 + ((g * 16) ^ ((ra & 3) << 4))];
      int rb = (mode == 0) ? (wn * 32 + (i & 1) * 16 + (i >> 1) * 64 + l15)
                           : (wn * 64 + i * 16 + l15);
      bf[i] = *(const int4v*)&Bs[rb * 64 + ((g * 16) ^ ((rb & 3) << 4))];
    }
#pragma unroll
    for (int mi = 0; mi < 4; ++mi)
#pragma unroll
      for (int ni = 0; ni < 4; ++ni)
        acc[mi][ni] = __builtin_amdgcn_mfma_i32_16x16x64_i8(af[mi], bf[ni], acc[mi][ni], 0, 0, 0);
  }

  if (mode == 0) {
    // fused rmsnorm + rope epilogue -> single fp16
    bool isq = (bn < 2048);
    int hh = isq ? (bn >> 7) : ((bn - 2048) >> 7);
    float wN = isq ? wsc[0] : wsc[1];
    float ps = isq ? 0.12751743075f : 1.0f;   // (1/sqrt(128))*log2(e) for q
    const float* nw = isq ? qn : kn;
    unsigned short* oh = isq ? qf : kf;
    int nhp = isq ? NHQ : NKVH;
    float* S = (float*)As;               // reuse LDS: [2][128] f32
    __syncthreads();                     // all waves done reading As/Bs
#pragma unroll
    for (int mi = 0; mi < 4; ++mi) {
#pragma unroll
      for (int rr = 0; rr < 4; ++rr) {
        int tok = bm + wm * 64 + mi * 16 + 4 * g + rr;
        float rs = asx[tok] * wN;
        float ssum = 0.f;
#pragma unroll
        for (int ni = 0; ni < 4; ++ni) {
          float v = (float)acc[mi][ni][rr] * rs;
          ssum += v * v;
        }
        ssum += __shfl_xor(ssum, 1); ssum += __shfl_xor(ssum, 2);
        ssum += __shfl_xor(ssum, 4); ssum += __shfl_xor(ssum, 8);
        if (l15 == 0) S[wn * 128 + wm * 64 + mi * 16 + 4 * g + rr] = ssum;
      }
    }
    __syncthreads();
#pragma unroll
    for (int mi = 0; mi < 4; ++mi) {
#pragma unroll
      for (int rr = 0; rr < 4; ++rr) {
        int rloc = wm * 64 + mi * 16 + 4 * g + rr;
        int tok = bm + rloc;
        float rs = asx[tok] * wN;
        float inv = rsqrtf((S[rloc] + S[128 + rloc]) * (1.f / 128.f) + 1e-6f);
        int s = tok & (SEQ - 1);
        float nv[4];
#pragma unroll
        for (int ni = 0; ni < 4; ++ni) {
          int d = wn * 32 + (ni & 1) * 16 + (ni >> 1) * 64 + l15;
          nv[ni] = nw[d] * ((float)acc[mi][ni][rr] * rs) * inv;
        }
#pragma unroll
        for (int ni = 0; ni < 4; ++ni) {
          int d = wn * 32 + (ni & 1) * 16 + (ni >> 1) * 64 + l15;
          float oo = nv[ni ^ 2];
          float rh = (ni < 2) ? -oo : oo;
          float res = (nv[ni] * cs[s * 128 + d] + rh * sn[s * 128 + d]) * ps;
          size_t oi = ((size_t)tok * nhp + hh) * 128 + d;
          oh[oi] = f2h(res);
        }
      }
    }
  } else if (mode == 2) {
#pragma unroll
    for (int mi = 0; mi < 4; ++mi) {
#pragma unroll
      for (int rr = 0; rr < 4; ++rr) {
        int crow = bm + wm * 64 + mi * 16 + 4 * g + rr;
        float rs = asx[crow] * wsc[3];
#pragma unroll
        for (int ni = 0; ni < 4; ++ni) {
          int ccol = bn + wn * 64 + ni * 16 + l15;
          d0[(size_t)crow * 2048 + ccol] = (float)acc[mi][ni][rr] * rs;
        }
      }
    }
  } else {   // mode 1: V fp16 transposed (crow=feature, ccol=token)
    float w2 = wsc[2];
#pragma unroll
    for (int mi = 0; mi < 4; ++mi) {
#pragma unroll
      for (int rr = 0; rr < 4; ++rr) {
        int crow = bm + wm * 64 + mi * 16 + 4 * g + rr;
#pragma unroll
        for (int ni = 0; ni < 4; ++ni) {
          int ccol = bn + wn * 64 + ni * 16 + l15;
          float v = (float)acc[mi][ni][rr] * asx[ccol] * w2;
          size_t ad = ((size_t)((ccol >> 10) * 1024 + crow)) * 1024 + (ccol & 1023);
          dh[ad] = f2h(v);
        }
      }
    }
  }
}

// ---------------------------------------------------------------------------
// K6: MFMA flash attention, persistent blocks + atomic work queue (LPT,
// heavy-first). All-fp16 operands, exp2 softmax, defer-max (per-lane check,
// reduce only on rescale). l accumulated via ones-row V MFMA (acc[8]) -> no
// psum shfls, no final l shfls. 4 waves/block, Q-tile 64, KV tile 32,
// double-buffered LDS via global_load_lds (source-side XOR swizzle).
// ---------------------------------------------------------------------------
__global__ __launch_bounds__(256) void k_attn_mfma(const unsigned short* __restrict__ qfp,
                                                   const unsigned short* __restrict__ kfp,
                                                   const unsigned short* __restrict__ vfp,
                                                   float* __restrict__ o,
                                                   int* __restrict__ ctr) {
  int tid = threadIdx.x;
  int wave = tid >> 6, lane = tid & 63;
  int l15 = lane & 15, g = lane >> 4;

  __shared__ unsigned short Kf[2][4096];     // fp16 K, [ki][d] swizzled
  __shared__ unsigned short Vf[2][4128];     // fp16 V^T [d][tok] swizzled + ones row @4096
  __shared__ unsigned short Plds[4][16][40]; // fp16 P transpose buffer
  __shared__ int s_u;

  // ones row (d=128) for l-accumulation via MFMA; never overwritten by STAGE
  if (tid < 32) {
    Vf[0][4096 + tid] = 0x3C00;
    Vf[1][4096 + tid] = 0x3C00;
  }

#define STAGE(KV0N, BFN)                                                              \
  {                                                                                   \
    int c0 = wave * 64 + lane;                                                        \
    _Pragma("unroll")                                                                 \
    for (int tch = 0; tch < 2; ++tch) {                                               \
      int c = tch * 256 + c0;                                                         \
      int ki = c >> 4, jb = (c & 15) << 4;                                            \
      int js = jb ^ ((ki & 7) << 4);                                                  \
      size_t kbase = ((size_t)(b * SEQ + (KV0N) + ki) * NKVH + kvh) * HDD;            \
      GLD_LDS16((const char*)(kfp + kbase) + js, &Kf[BFN][c * 8]);                    \
      int d = c >> 2, jv = (c & 3) << 4;                                              \
      int jvs = jv ^ ((d & 3) << 4);                                                  \
      size_t vbase = ((size_t)(b * 1024 + kvh * 128 + d)) * SEQ + (KV0N);             \
      GLD_LDS16((const char*)(vfp + vbase) + jvs, &Vf[BFN][c * 8]);                   \
    }                                                                                 \
  }

  while (true) {
    if (tid == 0) s_u = atomicAdd(ctr, 1);
    __syncthreads();                 // broadcast unit; also fences prev unit's LDS use
    int u = s_u;
    if (u >= 512) break;
    int qt = 15 - (u >> 5);          // heavy-first (LPT)
    int yy = u & 31;
    int b = yy >> 4, h = yy & 15, kvh = h >> 1;
    int q0w = qt * 64 + wave * 16;
    int qglob = q0w + l15;

    half8 qf[4];
    {
      const unsigned short* qb = qfp + ((size_t)(b * SEQ + qglob) * NHQ + h) * HDD + g * 8;
#pragma unroll
      for (int c = 0; c < 4; ++c) qf[c] = s2h(*(const short8*)(qb + c * 32));
    }

    f32x4 acc[9] = {};               // [0..7]=O d-tiles, [8]=l (ones-V)
    float m_run = -INFINITY;
    int nkv = 2 * qt + 2;

    STAGE(0, 0);
    __syncthreads();

    int bf = 0;
    for (int kv = 0; kv < nkv; ++kv) {
      int kv0 = kv * 32;
      if (kv + 1 < nkv) STAGE(kv0 + 32, bf ^ 1);
      bool active = (kv0 <= q0w + 15);
      if (active) {
        // ---- QK^T (fp16, scores in log2 units) ----
        float sc[2][4];
        __builtin_amdgcn_s_setprio(1);
#pragma unroll
        for (int t = 0; t < 2; ++t) {
          int row = 16 * t + l15;
          int rbyte = row * 256, sw = (row & 7) << 4;
          f32x4 s = {0.f, 0.f, 0.f, 0.f};
#pragma unroll
          for (int c = 0; c < 4; ++c) {
            int off = rbyte + ((c * 64 + g * 16) ^ sw);
            half8 kf8 = s2h(*(const short8*)((const char*)&Kf[bf][0] + off));
            s = __builtin_amdgcn_mfma_f32_16x16x32_f16(kf8, qf[c], s, 0, 0, 0);
          }
#pragma unroll
          for (int r = 0; r < 4; ++r) sc[t][r] = s[r];
        }
        __builtin_amdgcn_s_setprio(0);
        if (kv0 + 31 > q0w) {
#pragma unroll
          for (int t = 0; t < 2; ++t)
#pragma unroll
            for (int r = 0; r < 4; ++r)
              if (kv0 + 16 * t + 4 * g + r > qglob) sc[t][r] = -INFINITY;
        }
        // ---- online softmax (exp2; defer-max, per-lane check) ----
        float pmax = -INFINITY;
#pragma unroll
        for (int t = 0; t < 2; ++t)
#pragma unroll
          for (int r = 0; r < 4; ++r) pmax = fmaxf(pmax, sc[t][r]);
        if (!__all(pmax <= m_run + 10.f)) {
          pmax = fmaxf(pmax, __shfl_xor(pmax, 16));
          pmax = fmaxf(pmax, __shfl_xor(pmax, 32));
          float mnew = fmaxf(m_run, pmax);
          float corr = exp2f(m_run - mnew);
          m_run = mnew;
          float corro[4];
#pragma unroll
          for (int r = 0; r < 4; ++r) corro[r] = __shfl(corr, 4 * g + r);
#pragma unroll
          for (int dt = 0; dt < 9; ++dt)
#pragma unroll
            for (int r = 0; r < 4; ++r) acc[dt][r] *= corro[r];
        }
        unsigned short ph[2][4];
#pragma unroll
        for (int t = 0; t < 2; ++t)
#pragma unroll
          for (int r = 0; r < 4; ++r)
            ph[t][r] = f2h(exp2f(sc[t][r] - m_run));
        // ---- P transpose through per-wave LDS (fp16) ----
        ushort4 wh;
#pragma unroll
        for (int t = 0; t < 2; ++t) {
          wh.x = ph[t][0]; wh.y = ph[t][1]; wh.z = ph[t][2]; wh.w = ph[t][3];
          *(ushort4*)&Plds[wave][l15][16 * t + 4 * g] = wh;
        }
        half8 pa = s2h(*(const short8*)&Plds[wave][l15][8 * g]);
        // ---- PV (fp16) + l via ones row (dt==8) ----
        __builtin_amdgcn_s_setprio(1);
#pragma unroll
        for (int dt = 0; dt < 9; ++dt) {
          int off;
          if (dt < 8) {
            int d = dt * 16 + l15;
            off = d * 64 + ((g * 16) ^ ((d & 3) << 4));
          } else {
            off = 8192 + g * 16;   // ones row, broadcast within g-group
          }
          half8 vf8 = s2h(*(const short8*)((const char*)&Vf[bf][0] + off));
          acc[dt] = __builtin_amdgcn_mfma_f32_16x16x32_f16(pa, vf8, acc[dt], 0, 0, 0);
        }
        __builtin_amdgcn_s_setprio(0);
      }
      __syncthreads();
      bf ^= 1;
    }

    // ---- finalize: l available per-row in acc[8][r] (all cols equal) ----
    float linv[4];
#pragma unroll
    for (int r = 0; r < 4; ++r) linv[r] = 1.f / acc[8][r];
#pragma unroll
    for (int r = 0; r < 4; ++r) {
      size_t orow = ((size_t)(b * SEQ + q0w + 4 * g + r) * NHQ + h) * HDD + l15;
#pragma unroll
      for (int dt = 0; dt < 8; ++dt)
        o[orow + dt * 16] = acc[dt][r] * linv[r];
    }
  }
#undef STAGE
}

// ---------------------------------------------------------------------------
extern "C" void kernel_launch(void* const* d_in, const int* in_sizes, int n_in,
                              void* d_out, int out_size, void* d_ws, size_t ws_size,
                              hipStream_t stream) {
  const float* x  = (const float*)d_in[0];
  const float* cs = (const float*)d_in[1];
  const float* sn = (const float*)d_in[2];
  const float* wq = (const float*)d_in[3];
  const float* wk = (const float*)d_in[4];
  const float* wv = (const float*)d_in[5];
  const float* wo = (const float*)d_in[6];
  const float* qn = (const float*)d_in[7];
  const float* kn = (const float*)d_in[8];
  float* out = (float*)d_out;
  char* ws = (char*)d_ws;

  const size_t MB = 1024 * 1024;
  size_t o_xq  = 0;            // 4 MB  int8 xq
  size_t o_wqk = 4  * MB;      // 6 MB  [3072][2048] i8
  size_t o_wvt = 10 * MB;      // 2 MB  [1024][2048] i8
  size_t o_wot = 12 * MB;      // 4 MB  [2048][2048] i8
  size_t o_vt  = 16 * MB;      // 4 MB  fp16 V transposed
  size_t o_qf  = 20 * MB;      // 8 MB  fp16 q (rope'd, log2e/sqrt(128) folded)
  size_t o_kf  = 28 * MB;      // 4 MB  fp16 k (rope'd)
  size_t o_ao  = 32 * MB;      // 16 MB f32 attn out
  size_t o_aq  = 48 * MB;      // 4 MB  int8 requant
  size_t o_as  = 52 * MB;
  size_t o_as2 = o_as  + 8192;
  size_t o_prt = o_as2 + 8192;
  size_t o_wsc = o_prt + 8192;
  size_t o_ctr = o_wsc + 4096;

  signed char* xq  = (signed char*)(ws + o_xq);
  signed char* wqk = (signed char*)(ws + o_wqk);
  signed char* wvt = (signed char*)(ws + o_wvt);
  signed char* wot = (signed char*)(ws + o_wot);
  unsigned short* vt = (unsigned short*)(ws + o_vt);
  unsigned short* qf = (unsigned short*)(ws + o_qf);
  unsigned short* kf = (unsigned short*)(ws + o_kf);
  float* ao = (float*)(ws + o_ao);
  signed char* aq = (signed char*)(ws + o_aq);
  float* asx = (float*)(ws + o_as);
  float* as2 = (float*)(ws + o_as2);
  double* prt = (double*)(ws + o_prt);
  float* wsc = (float*)(ws + o_wsc);
  int* ctr = (int*)(ws + o_ctr);

  // 1) activation quant of x -> int8
  k_actquant<<<TT, 256, 0, stream>>>(x, xq, asx);

  // 2) weight scales
  k_absum_all<<<dim3(256, 4), 256, 0, stream>>>(wq, wk, wv, wo, prt);
  k_wscale<<<1, 256, 0, stream>>>(prt, wsc);

  // 3) ternary weight quant -> int8
  k_wquant_all<<<2048, 256, 0, stream>>>(wq, wk, wv, wo, wqk, wvt, wot, wsc);

  // 4) fused QKV projection + rmsnorm/rope epilogue (one dispatch)
  k_gemm_i8<<<512, 256, 0, stream>>>(xq, wqk, wvt, 0, nullptr, vt, asx, wsc,
                                     qn, kn, cs, sn, qf, kf);

  // 5) MFMA flash attention (persistent + atomic queue)
  hipMemsetAsync(ctr, 0, 4, stream);
  k_attn_mfma<<<512, 256, 0, stream>>>(qf, kf, vt, ao, ctr);

  // 6) re-quant + output projection
  k_actquant<<<TT, 256, 0, stream>>>(ao, aq, as2);
  k_gemm_i8<<<256, 256, 0, stream>>>(aq, wot, nullptr, 1, out, nullptr, as2, wsc,
                                     nullptr, nullptr, nullptr, nullptr,
                                     nullptr, nullptr);
}

// Round 9
// 141.464 us; speedup vs baseline: 1.0452x; 1.0452x over previous
//
#include <hip/hip_runtime.h>
#include <hip/hip_bf16.h>

#define TT   2048   // B*S tokens
#define HH   2048   // hidden dim
#define SEQ  1024
#define NHQ  16
#define NKVH 8
#define HDD  128

typedef __attribute__((ext_vector_type(8))) short short8;
typedef __attribute__((ext_vector_type(4))) float f32x4;
typedef __attribute__((ext_vector_type(4))) int int4v;
typedef _Float16 half8 __attribute__((ext_vector_type(8)));

static __device__ __forceinline__ unsigned short f2h(float f) {
  union { _Float16 h; unsigned short u; } c;
  c.h = (_Float16)f;
  return c.u;
}
static __device__ __forceinline__ half8 s2h(short8 v) {
  union { short8 s; half8 h; } c;
  c.s = v;
  return c.h;
}

#define GLD_LDS16(gp, lp)                                                        \
  __builtin_amdgcn_global_load_lds(                                              \
      (const __attribute__((address_space(1))) void*)(const void*)(gp),          \
      (__attribute__((address_space(3))) void*)(void*)(lp), 16, 0, 0)

// ---------------------------------------------------------------------------
// K1: per-row act_quant -> int8 (vectorized float4 loads, shfl reduce)
// ---------------------------------------------------------------------------
__global__ __launch_bounds__(256) void k_actquant(const float* __restrict__ x,
                                                  signed char* __restrict__ xq,
                                                  float* __restrict__ as_inv) {
  int row = blockIdx.x, tid = threadIdx.x;
  int wave = tid >> 6, lane = tid & 63;
  const float4* xr4 = (const float4*)(x + (size_t)row * HH);
  float4 a = xr4[tid * 2], b = xr4[tid * 2 + 1];
  float am = fmaxf(fmaxf(fmaxf(fabsf(a.x), fabsf(a.y)), fmaxf(fabsf(a.z), fabsf(a.w))),
                   fmaxf(fmaxf(fabsf(b.x), fabsf(b.y)), fmaxf(fabsf(b.z), fabsf(b.w))));
#pragma unroll
  for (int o = 32; o; o >>= 1) am = fmaxf(am, __shfl_xor(am, o));
  __shared__ float wred[4];
  if (lane == 0) wred[wave] = am;
  __syncthreads();
  am = fmaxf(fmaxf(wred[0], wred[1]), fmaxf(wred[2], wred[3]));
  am = fmaxf(am, 1e-5f);
  if (tid == 0) as_inv[row] = am / 127.f;
  float scale = 127.f / am;
  float vals[8] = {a.x, a.y, a.z, a.w, b.x, b.y, b.z, b.w};
  unsigned int u0 = 0, u1 = 0;
#pragma unroll
  for (int j = 0; j < 4; ++j) {
    int q = (int)fminf(fmaxf(rintf(vals[j] * scale), -128.f), 127.f);
    u0 |= (unsigned int)(q & 255) << (8 * j);
  }
#pragma unroll
  for (int j = 0; j < 4; ++j) {
    int q = (int)fminf(fmaxf(rintf(vals[4 + j] * scale), -128.f), 127.f);
    u1 |= (unsigned int)(q & 255) << (8 * j);
  }
  uint2 uu; uu.x = u0; uu.y = u1;
  ((uint2*)(xq + (size_t)row * HH))[tid] = uu;
}

// ---------------------------------------------------------------------------
// K2: deterministic partial |w| sums (f64), all 4 weights in one dispatch
// ---------------------------------------------------------------------------
__global__ __launch_bounds__(256) void k_absum_all(const float* __restrict__ wq,
                                                   const float* __restrict__ wk,
                                                   const float* __restrict__ wv,
                                                   const float* __restrict__ wo,
                                                   double* __restrict__ part) {
  int wid = blockIdx.y;
  const float* w = (wid == 0) ? wq : (wid == 1) ? wk : (wid == 2) ? wv : wo;
  int nq = ((wid == 0 || wid == 3) ? 4194304 : 2097152) >> 2;
  double s = 0.0;
  for (int i = blockIdx.x * 256 + threadIdx.x; i < nq; i += 256 * 256) {
    float4 v = ((const float4*)w)[i];
    s += (double)fabsf(v.x) + (double)fabsf(v.y) + (double)fabsf(v.z) + (double)fabsf(v.w);
  }
  __shared__ double red[256];
  red[threadIdx.x] = s;
  __syncthreads();
  for (int st = 128; st > 0; st >>= 1) {
    if (threadIdx.x < st) red[threadIdx.x] += red[threadIdx.x + st];
    __syncthreads();
  }
  if (threadIdx.x == 0) part[wid * 256 + blockIdx.x] = red[0];
}

__global__ __launch_bounds__(256) void k_wscale(const double* __restrict__ part,
                                                float* __restrict__ wsc) {
  __shared__ double red[256];
  const double nvals[4] = {4194304.0, 2097152.0, 2097152.0, 4194304.0};
  for (int w = 0; w < 4; ++w) {
    red[threadIdx.x] = part[w * 256 + threadIdx.x];
    __syncthreads();
    for (int st = 128; st > 0; st >>= 1) {
      if (threadIdx.x < st) red[threadIdx.x] += red[threadIdx.x + st];
      __syncthreads();
    }
    if (threadIdx.x == 0) {
      float mean = (float)(red[0] / nvals[w]);
      wsc[w] = fmaxf(mean, 1e-5f);
    }
    __syncthreads();
  }
}

// ---------------------------------------------------------------------------
// K3: ternary weight quant -> int8, all 4 weights in one dispatch
// ---------------------------------------------------------------------------
__global__ __launch_bounds__(256) void k_wquant_all(const float* __restrict__ wq,
                                                    const float* __restrict__ wk,
                                                    const float* __restrict__ wv,
                                                    const float* __restrict__ wo,
                                                    signed char* __restrict__ wqk,
                                                    signed char* __restrict__ wvt,
                                                    signed char* __restrict__ wot,
                                                    const float* __restrict__ wsc) {
  const int NQ = 3145728;
  for (int qi = blockIdx.x * 256 + threadIdx.x; qi < NQ; qi += gridDim.x * 256) {
    const float* src; signed char* dst; float inv; int off;
    if (qi < 1048576)      { src = wq; dst = wqk;           off = qi;           inv = 1.f / wsc[0]; }
    else if (qi < 1572864) { src = wk; dst = wqk + 4194304; off = qi - 1048576; inv = 1.f / wsc[1]; }
    else if (qi < 2097152) { src = wv; dst = wvt;           off = qi - 1572864; inv = 1.f / wsc[2]; }
    else                   { src = wo; dst = wot;           off = qi - 2097152; inv = 1.f / wsc[3]; }
    float4 v = ((const float4*)src)[off];
    unsigned int u = 0;
    float vv[4] = {v.x, v.y, v.z, v.w};
#pragma unroll
    for (int j = 0; j < 4; ++j) {
      int q = (int)fminf(fmaxf(rintf(vv[j] * inv), -1.f), 1.f);
      u |= (unsigned int)(q & 255) << (8 * j);
    }
    ((unsigned int*)dst)[off] = u;
  }
}

// ---------------------------------------------------------------------------
// K4: i8 MFMA NT-GEMM, 128x128 tile, BK=64, global_load_lds staging,
// source-side XOR swizzle. (unchanged)
// ---------------------------------------------------------------------------
__global__ __launch_bounds__(256) void k_gemm_i8(const signed char* __restrict__ A0,
                                                 const signed char* __restrict__ B0,
                                                 const signed char* __restrict__ B1,
                                                 int which,
                                                 float* __restrict__ d0,
                                                 unsigned short* __restrict__ dh,
                                                 const float* __restrict__ asx,
                                                 const float* __restrict__ wsc,
                                                 const float* __restrict__ qn,
                                                 const float* __restrict__ kn,
                                                 const float* __restrict__ cs,
                                                 const float* __restrict__ sn,
                                                 unsigned short* __restrict__ qf,
                                                 unsigned short* __restrict__ kf) {
  const int K = HH;
  __shared__ signed char As[8192];   // [128][64] (source-swizzled within rows)
  __shared__ signed char Bs[8192];
  int tid = threadIdx.x;
  int wave = tid >> 6, lane = tid & 63, l15 = lane & 15, g = lane >> 4;
  int wm = wave >> 1, wn = wave & 1;

  const signed char *Ap, *Bp;
  int bm, bn, mode;
  if (which == 0) {
    int gid = (blockIdx.x & 7) * 64 + (blockIdx.x >> 3);   // XCD chunk, 512 blocks
    if (gid < 384) { mode = 0; bm = (gid / 24) * 128; bn = (gid % 24) * 128; Ap = A0; Bp = B0; }
    else { mode = 1; int vid = gid - 384; bm = (vid >> 4) * 128; bn = (vid & 15) * 128; Ap = B1; Bp = A0; }
  } else {
    int gid = (blockIdx.x & 7) * 32 + (blockIdx.x >> 3);   // 256 blocks
    mode = 2; bm = (gid >> 4) * 128; bn = (gid & 15) * 128; Ap = A0; Bp = B0;
  }

  int4v acc[4][4] = {};
  for (int k0 = 0; k0 < K; k0 += 64) {
    __syncthreads();
#pragma unroll
    for (int r = 0; r < 2; ++r) {
      int c = r * 256 + tid;
      int row = c >> 2;
      int kk = ((c & 3) << 4) ^ ((row & 3) << 4);
      GLD_LDS16(Ap + (size_t)(bm + row) * K + k0 + kk, As + c * 16);
      GLD_LDS16(Bp + (size_t)(bn + row) * K + k0 + kk, Bs + c * 16);
    }
    __syncthreads();
    int4v af[4], bf[4];
#pragma unroll
    for (int i = 0; i < 4; ++i) {
      int ra = wm * 64 + i * 16 + l15;
      af[i] = *(const int4v*)&As[ra * 64 + ((g * 16) ^ ((ra & 3) << 4))];
      int rb = (mode == 0) ? (wn * 32 + (i & 1) * 16 + (i >> 1) * 64 + l15)
                           : (wn * 64 + i * 16 + l15);
      bf[i] = *(const int4v*)&Bs[rb * 64 + ((g * 16) ^ ((rb & 3) << 4))];
    }
#pragma unroll
    for (int mi = 0; mi < 4; ++mi)
#pragma unroll
      for (int ni = 0; ni < 4; ++ni)
        acc[mi][ni] = __builtin_amdgcn_mfma_i32_16x16x64_i8(af[mi], bf[ni], acc[mi][ni], 0, 0, 0);
  }

  if (mode == 0) {
    // fused rmsnorm + rope epilogue -> single fp16
    bool isq = (bn < 2048);
    int hh = isq ? (bn >> 7) : ((bn - 2048) >> 7);
    float wN = isq ? wsc[0] : wsc[1];
    float ps = isq ? 0.12751743075f : 1.0f;   // (1/sqrt(128))*log2(e) for q
    const float* nw = isq ? qn : kn;
    unsigned short* oh = isq ? qf : kf;
    int nhp = isq ? NHQ : NKVH;
    float* S = (float*)As;               // reuse LDS: [2][128] f32
    __syncthreads();                     // all waves done reading As/Bs
#pragma unroll
    for (int mi = 0; mi < 4; ++mi) {
#pragma unroll
      for (int rr = 0; rr < 4; ++rr) {
        int tok = bm + wm * 64 + mi * 16 + 4 * g + rr;
        float rs = asx[tok] * wN;
        float ssum = 0.f;
#pragma unroll
        for (int ni = 0; ni < 4; ++ni) {
          float v = (float)acc[mi][ni][rr] * rs;
          ssum += v * v;
        }
        ssum += __shfl_xor(ssum, 1); ssum += __shfl_xor(ssum, 2);
        ssum += __shfl_xor(ssum, 4); ssum += __shfl_xor(ssum, 8);
        if (l15 == 0) S[wn * 128 + wm * 64 + mi * 16 + 4 * g + rr] = ssum;
      }
    }
    __syncthreads();
#pragma unroll
    for (int mi = 0; mi < 4; ++mi) {
#pragma unroll
      for (int rr = 0; rr < 4; ++rr) {
        int rloc = wm * 64 + mi * 16 + 4 * g + rr;
        int tok = bm + rloc;
        float rs = asx[tok] * wN;
        float inv = rsqrtf((S[rloc] + S[128 + rloc]) * (1.f / 128.f) + 1e-6f);
        int s = tok & (SEQ - 1);
        float nv[4];
#pragma unroll
        for (int ni = 0; ni < 4; ++ni) {
          int d = wn * 32 + (ni & 1) * 16 + (ni >> 1) * 64 + l15;
          nv[ni] = nw[d] * ((float)acc[mi][ni][rr] * rs) * inv;
        }
#pragma unroll
        for (int ni = 0; ni < 4; ++ni) {
          int d = wn * 32 + (ni & 1) * 16 + (ni >> 1) * 64 + l15;
          float oo = nv[ni ^ 2];
          float rh = (ni < 2) ? -oo : oo;
          float res = (nv[ni] * cs[s * 128 + d] + rh * sn[s * 128 + d]) * ps;
          size_t oi = ((size_t)tok * nhp + hh) * 128 + d;
          oh[oi] = f2h(res);
        }
      }
    }
  } else if (mode == 2) {
#pragma unroll
    for (int mi = 0; mi < 4; ++mi) {
#pragma unroll
      for (int rr = 0; rr < 4; ++rr) {
        int crow = bm + wm * 64 + mi * 16 + 4 * g + rr;
        float rs = asx[crow] * wsc[3];
#pragma unroll
        for (int ni = 0; ni < 4; ++ni) {
          int ccol = bn + wn * 64 + ni * 16 + l15;
          d0[(size_t)crow * 2048 + ccol] = (float)acc[mi][ni][rr] * rs;
        }
      }
    }
  } else {   // mode 1: V fp16 transposed (crow=feature, ccol=token)
    float w2 = wsc[2];
#pragma unroll
    for (int mi = 0; mi < 4; ++mi) {
#pragma unroll
      for (int rr = 0; rr < 4; ++rr) {
        int crow = bm + wm * 64 + mi * 16 + 4 * g + rr;
#pragma unroll
        for (int ni = 0; ni < 4; ++ni) {
          int ccol = bn + wn * 64 + ni * 16 + l15;
          float v = (float)acc[mi][ni][rr] * asx[ccol] * w2;
          size_t ad = ((size_t)((ccol >> 10) * 1024 + crow)) * 1024 + (ccol & 1023);
          dh[ad] = f2h(v);
        }
      }
    }
  }
}

// ---------------------------------------------------------------------------
// K6: MFMA flash attention. Static XCD-chunked dispatch (r7 schedule, best L2
// locality). All-fp16 operands, exp2 softmax, per-lane defer-max, l via
// constant-ones MFMA (acc[8]). 3-buffer LDS pipeline, 2 tiles in flight:
// raw s_barrier + counted s_waitcnt vmcnt(4) (never 0 in steady state) so
// staging loads get a full iteration of latency cover. 53.8 KB LDS ->
// 3 blocks/CU.
// ---------------------------------------------------------------------------
__global__ __launch_bounds__(256) void k_attn_mfma(const unsigned short* __restrict__ qfp,
                                                   const unsigned short* __restrict__ kfp,
                                                   const unsigned short* __restrict__ vfp,
                                                   float* __restrict__ o) {
  int chunk = blockIdx.x & 7, j = blockIdx.x >> 3;   // XCD, within-chunk
  int qt = 15 - (j >> 2);                            // heavy first in launch order
  int yy = (chunk << 2) + (j & 3);                   // 4 heads/chunk share L2
  int b = yy >> 4, h = yy & 15, kvh = h >> 1;
  int tid = threadIdx.x;
  int wave = tid >> 6, lane = tid & 63;
  int l15 = lane & 15, g = lane >> 4;
  int q0w = qt * 64 + wave * 16;
  int qglob = q0w + l15;

  __shared__ unsigned short Kf[3][4096];     // fp16 K, [ki][d] swizzled
  __shared__ unsigned short Vf[3][4096];     // fp16 V^T [d][tok] swizzled
  __shared__ unsigned short Plds[4][16][36]; // fp16 P transpose buffer

  half8 qf[4];
  {
    const unsigned short* qb = qfp + ((size_t)(b * SEQ + qglob) * NHQ + h) * HDD + g * 8;
#pragma unroll
    for (int c = 0; c < 4; ++c) qf[c] = s2h(*(const short8*)(qb + c * 32));
  }
  half8 vones;
#pragma unroll
  for (int c = 0; c < 8; ++c) vones[c] = (_Float16)1.0f;

  // STAGE: exactly 4 VMEM ops per thread (2 K + 2 V chunks of 16 B)
#define STAGE(KV0N, BUF)                                                              \
  {                                                                                   \
    int c0 = wave * 64 + lane;                                                        \
    _Pragma("unroll")                                                                 \
    for (int tch = 0; tch < 2; ++tch) {                                               \
      int c = tch * 256 + c0;                                                         \
      int ki = c >> 4, jb = (c & 15) << 4;                                            \
      int js = jb ^ ((ki & 7) << 4);                                                  \
      size_t kbase = ((size_t)(b * SEQ + (KV0N) + ki) * NKVH + kvh) * HDD;            \
      GLD_LDS16((const char*)(kfp + kbase) + js, &Kf[BUF][c * 8]);                    \
      int d = c >> 2, jv = (c & 3) << 4;                                              \
      int jvs = jv ^ ((d & 3) << 4);                                                  \
      size_t vbase = ((size_t)(b * 1024 + kvh * 128 + d)) * SEQ + (KV0N);             \
      GLD_LDS16((const char*)(vfp + vbase) + jvs, &Vf[BUF][c * 8]);                   \
    }                                                                                 \
  }

  f32x4 acc[9] = {};                 // [0..7]=O d-tiles, [8]=l (ones-V)
  float m_run = -INFINITY;
  int nkv = 2 * qt + 2;

  // prologue: stage tiles 0 and 1; wait only for tile 0 (vmcnt(4) leaves
  // tile 1's 4 loads in flight)
  STAGE(0, 0);
  STAGE(32, 1);
  asm volatile("s_waitcnt vmcnt(4) lgkmcnt(0)" ::: "memory");
  __builtin_amdgcn_s_barrier();
  __builtin_amdgcn_sched_barrier(0);

  int cur = 0, nxt = 1, nx2 = 2;
  for (int kv = 0; kv < nkv; ++kv) {
    int kv0 = kv * 32;
    bool more = (kv + 2 < nkv);
    if (more) STAGE(kv0 + 64, nx2);          // 2-ahead into third buffer
    bool active = (kv0 <= q0w + 15);
    if (active) {
      const char* Kb = (const char*)&Kf[cur][0];
      const char* Vb = (const char*)&Vf[cur][0];
      // ---- QK^T (fp16, scores in log2 units) ----
      float sc[2][4];
      __builtin_amdgcn_s_setprio(1);
#pragma unroll
      for (int t = 0; t < 2; ++t) {
        int row = 16 * t + l15;
        int rbyte = row * 256, sw = (row & 7) << 4;
        f32x4 s = {0.f, 0.f, 0.f, 0.f};
#pragma unroll
        for (int c = 0; c < 4; ++c) {
          int off = rbyte + ((c * 64 + g * 16) ^ sw);
          half8 kf8 = s2h(*(const short8*)(Kb + off));
          s = __builtin_amdgcn_mfma_f32_16x16x32_f16(kf8, qf[c], s, 0, 0, 0);
        }
#pragma unroll
        for (int r = 0; r < 4; ++r) sc[t][r] = s[r];
      }
      __builtin_amdgcn_s_setprio(0);
      if (kv0 + 31 > q0w) {
#pragma unroll
        for (int t = 0; t < 2; ++t)
#pragma unroll
          for (int r = 0; r < 4; ++r)
            if (kv0 + 16 * t + 4 * g + r > qglob) sc[t][r] = -INFINITY;
      }
      // ---- online softmax (exp2; defer-max, per-lane check) ----
      float pmax = -INFINITY;
#pragma unroll
      for (int t = 0; t < 2; ++t)
#pragma unroll
        for (int r = 0; r < 4; ++r) pmax = fmaxf(pmax, sc[t][r]);
      if (!__all(pmax <= m_run + 10.f)) {
        pmax = fmaxf(pmax, __shfl_xor(pmax, 16));
        pmax = fmaxf(pmax, __shfl_xor(pmax, 32));
        float mnew = fmaxf(m_run, pmax);
        float corr = exp2f(m_run - mnew);
        m_run = mnew;
        float corro[4];
#pragma unroll
        for (int r = 0; r < 4; ++r) corro[r] = __shfl(corr, 4 * g + r);
#pragma unroll
        for (int dt = 0; dt < 9; ++dt)
#pragma unroll
          for (int r = 0; r < 4; ++r) acc[dt][r] *= corro[r];
      }
      unsigned short ph[2][4];
#pragma unroll
      for (int t = 0; t < 2; ++t)
#pragma unroll
        for (int r = 0; r < 4; ++r)
          ph[t][r] = f2h(exp2f(sc[t][r] - m_run));
      // ---- P transpose through per-wave LDS (fp16) ----
      ushort4 wh;
#pragma unroll
      for (int t = 0; t < 2; ++t) {
        wh.x = ph[t][0]; wh.y = ph[t][1]; wh.z = ph[t][2]; wh.w = ph[t][3];
        *(ushort4*)&Plds[wave][l15][16 * t + 4 * g] = wh;
      }
      half8 pa = s2h(*(const short8*)&Plds[wave][l15][8 * g]);
      // ---- PV (fp16) + l via constant-ones MFMA ----
      __builtin_amdgcn_s_setprio(1);
#pragma unroll
      for (int dt = 0; dt < 8; ++dt) {
        int d = dt * 16 + l15;
        int off = d * 64 + ((g * 16) ^ ((d & 3) << 4));
        half8 vf8 = s2h(*(const short8*)(Vb + off));
        acc[dt] = __builtin_amdgcn_mfma_f32_16x16x32_f16(pa, vf8, acc[dt], 0, 0, 0);
      }
      acc[8] = __builtin_amdgcn_mfma_f32_16x16x32_f16(pa, vones, acc[8], 0, 0, 0);
      __builtin_amdgcn_s_setprio(0);
    }
    // counted-vmcnt barrier: tile kv+1 guaranteed complete, tile kv+2's
    // 4 loads stay in flight across the barrier
    if (more) { asm volatile("s_waitcnt vmcnt(4)" ::: "memory"); }
    else      { asm volatile("s_waitcnt vmcnt(0)" ::: "memory"); }
    __builtin_amdgcn_s_barrier();
    __builtin_amdgcn_sched_barrier(0);
    int t0 = cur; cur = nxt; nxt = nx2; nx2 = t0;
  }
#undef STAGE

  // ---- finalize: l per-row in acc[8][r] ----
  float linv[4];
#pragma unroll
  for (int r = 0; r < 4; ++r) linv[r] = 1.f / acc[8][r];
#pragma unroll
  for (int r = 0; r < 4; ++r) {
    size_t orow = ((size_t)(b * SEQ + q0w + 4 * g + r) * NHQ + h) * HDD + l15;
#pragma unroll
    for (int dt = 0; dt < 8; ++dt)
      o[orow + dt * 16] = acc[dt][r] * linv[r];
  }
}

// ---------------------------------------------------------------------------
extern "C" void kernel_launch(void* const* d_in, const int* in_sizes, int n_in,
                              void* d_out, int out_size, void* d_ws, size_t ws_size,
                              hipStream_t stream) {
  const float* x  = (const float*)d_in[0];
  const float* cs = (const float*)d_in[1];
  const float* sn = (const float*)d_in[2];
  const float* wq = (const float*)d_in[3];
  const float* wk = (const float*)d_in[4];
  const float* wv = (const float*)d_in[5];
  const float* wo = (const float*)d_in[6];
  const float* qn = (const float*)d_in[7];
  const float* kn = (const float*)d_in[8];
  float* out = (float*)d_out;
  char* ws = (char*)d_ws;

  const size_t MB = 1024 * 1024;
  size_t o_xq  = 0;            // 4 MB  int8 xq
  size_t o_wqk = 4  * MB;      // 6 MB  [3072][2048] i8
  size_t o_wvt = 10 * MB;      // 2 MB  [1024][2048] i8
  size_t o_wot = 12 * MB;      // 4 MB  [2048][2048] i8
  size_t o_vt  = 16 * MB;      // 4 MB  fp16 V transposed
  size_t o_qf  = 20 * MB;      // 8 MB  fp16 q (rope'd, log2e/sqrt(128) folded)
  size_t o_kf  = 28 * MB;      // 4 MB  fp16 k (rope'd)
  size_t o_ao  = 32 * MB;      // 16 MB f32 attn out
  size_t o_aq  = 48 * MB;      // 4 MB  int8 requant
  size_t o_as  = 52 * MB;
  size_t o_as2 = o_as  + 8192;
  size_t o_prt = o_as2 + 8192;
  size_t o_wsc = o_prt + 8192;

  signed char* xq  = (signed char*)(ws + o_xq);
  signed char* wqk = (signed char*)(ws + o_wqk);
  signed char* wvt = (signed char*)(ws + o_wvt);
  signed char* wot = (signed char*)(ws + o_wot);
  unsigned short* vt = (unsigned short*)(ws + o_vt);
  unsigned short* qf = (unsigned short*)(ws + o_qf);
  unsigned short* kf = (unsigned short*)(ws + o_kf);
  float* ao = (float*)(ws + o_ao);
  signed char* aq = (signed char*)(ws + o_aq);
  float* asx = (float*)(ws + o_as);
  float* as2 = (float*)(ws + o_as2);
  double* prt = (double*)(ws + o_prt);
  float* wsc = (float*)(ws + o_wsc);

  // 1) activation quant of x -> int8
  k_actquant<<<TT, 256, 0, stream>>>(x, xq, asx);

  // 2) weight scales
  k_absum_all<<<dim3(256, 4), 256, 0, stream>>>(wq, wk, wv, wo, prt);
  k_wscale<<<1, 256, 0, stream>>>(prt, wsc);

  // 3) ternary weight quant -> int8
  k_wquant_all<<<2048, 256, 0, stream>>>(wq, wk, wv, wo, wqk, wvt, wot, wsc);

  // 4) fused QKV projection + rmsnorm/rope epilogue (one dispatch)
  k_gemm_i8<<<512, 256, 0, stream>>>(xq, wqk, wvt, 0, nullptr, vt, asx, wsc,
                                     qn, kn, cs, sn, qf, kf);

  // 5) MFMA flash attention (static schedule, 3-buffer counted-vmcnt pipeline)
  k_attn_mfma<<<512, 256, 0, stream>>>(qf, kf, vt, ao);

  // 6) re-quant + output projection
  k_actquant<<<TT, 256, 0, stream>>>(ao, aq, as2);
  k_gemm_i8<<<256, 256, 0, stream>>>(aq, wot, nullptr, 1, out, nullptr, as2, wsc,
                                     nullptr, nullptr, nullptr, nullptr,
                                     nullptr, nullptr);
}

// Round 10
// 138.157 us; speedup vs baseline: 1.0702x; 1.0239x over previous
//
#include <hip/hip_runtime.h>
#include <hip/hip_bf16.h>

#define TT   2048   // B*S tokens
#define HH   2048   // hidden dim
#define SEQ  1024
#define NHQ  16
#define NKVH 8
#define HDD  128

typedef __attribute__((ext_vector_type(8))) short short8;
typedef __attribute__((ext_vector_type(4))) float f32x4;
typedef __attribute__((ext_vector_type(4))) int int4v;
typedef _Float16 half8 __attribute__((ext_vector_type(8)));

static __device__ __forceinline__ unsigned short f2h(float f) {
  union { _Float16 h; unsigned short u; } c;
  c.h = (_Float16)f;
  return c.u;
}
static __device__ __forceinline__ half8 s2h(short8 v) {
  union { short8 s; half8 h; } c;
  c.s = v;
  return c.h;
}

#define GLD_LDS16(gp, lp)                                                        \
  __builtin_amdgcn_global_load_lds(                                              \
      (const __attribute__((address_space(1))) void*)(const void*)(gp),          \
      (__attribute__((address_space(3))) void*)(void*)(lp), 16, 0, 0)

// ---------------------------------------------------------------------------
// K1: per-row act_quant -> int8 (vectorized float4 loads, shfl reduce)
// ---------------------------------------------------------------------------
__global__ __launch_bounds__(256) void k_actquant(const float* __restrict__ x,
                                                  signed char* __restrict__ xq,
                                                  float* __restrict__ as_inv) {
  int row = blockIdx.x, tid = threadIdx.x;
  int wave = tid >> 6, lane = tid & 63;
  const float4* xr4 = (const float4*)(x + (size_t)row * HH);
  float4 a = xr4[tid * 2], b = xr4[tid * 2 + 1];
  float am = fmaxf(fmaxf(fmaxf(fabsf(a.x), fabsf(a.y)), fmaxf(fabsf(a.z), fabsf(a.w))),
                   fmaxf(fmaxf(fabsf(b.x), fabsf(b.y)), fmaxf(fabsf(b.z), fabsf(b.w))));
#pragma unroll
  for (int o = 32; o; o >>= 1) am = fmaxf(am, __shfl_xor(am, o));
  __shared__ float wred[4];
  if (lane == 0) wred[wave] = am;
  __syncthreads();
  am = fmaxf(fmaxf(wred[0], wred[1]), fmaxf(wred[2], wred[3]));
  am = fmaxf(am, 1e-5f);
  if (tid == 0) as_inv[row] = am / 127.f;
  float scale = 127.f / am;
  float vals[8] = {a.x, a.y, a.z, a.w, b.x, b.y, b.z, b.w};
  unsigned int u0 = 0, u1 = 0;
#pragma unroll
  for (int j = 0; j < 4; ++j) {
    int q = (int)fminf(fmaxf(rintf(vals[j] * scale), -128.f), 127.f);
    u0 |= (unsigned int)(q & 255) << (8 * j);
  }
#pragma unroll
  for (int j = 0; j < 4; ++j) {
    int q = (int)fminf(fmaxf(rintf(vals[4 + j] * scale), -128.f), 127.f);
    u1 |= (unsigned int)(q & 255) << (8 * j);
  }
  uint2 uu; uu.x = u0; uu.y = u1;
  ((uint2*)(xq + (size_t)row * HH))[tid] = uu;
}

// ---------------------------------------------------------------------------
// K2: deterministic partial |w| sums (f64), all 4 weights in one dispatch
// ---------------------------------------------------------------------------
__global__ __launch_bounds__(256) void k_absum_all(const float* __restrict__ wq,
                                                   const float* __restrict__ wk,
                                                   const float* __restrict__ wv,
                                                   const float* __restrict__ wo,
                                                   double* __restrict__ part) {
  int wid = blockIdx.y;
  const float* w = (wid == 0) ? wq : (wid == 1) ? wk : (wid == 2) ? wv : wo;
  int nq = ((wid == 0 || wid == 3) ? 4194304 : 2097152) >> 2;
  double s = 0.0;
  for (int i = blockIdx.x * 256 + threadIdx.x; i < nq; i += 256 * 256) {
    float4 v = ((const float4*)w)[i];
    s += (double)fabsf(v.x) + (double)fabsf(v.y) + (double)fabsf(v.z) + (double)fabsf(v.w);
  }
  __shared__ double red[256];
  red[threadIdx.x] = s;
  __syncthreads();
  for (int st = 128; st > 0; st >>= 1) {
    if (threadIdx.x < st) red[threadIdx.x] += red[threadIdx.x + st];
    __syncthreads();
  }
  if (threadIdx.x == 0) part[wid * 256 + blockIdx.x] = red[0];
}

// ---------------------------------------------------------------------------
// K3: ternary weight quant -> int8, all 4 weights in one dispatch.
// Each block recomputes the 4 scales from the f64 partials (deterministic,
// identical in every block); block 0 publishes wsc for the GEMMs. Kills the
// separate 1-block k_wscale launch bubble.
// ---------------------------------------------------------------------------
__global__ __launch_bounds__(256) void k_wquant_all(const float* __restrict__ wq,
                                                    const float* __restrict__ wk,
                                                    const float* __restrict__ wv,
                                                    const float* __restrict__ wo,
                                                    signed char* __restrict__ wqk,
                                                    signed char* __restrict__ wvt,
                                                    signed char* __restrict__ wot,
                                                    const double* __restrict__ part,
                                                    float* __restrict__ wsc) {
  int tid = threadIdx.x;
  int wave = tid >> 6, lane = tid & 63;
  __shared__ double wred[4][4];
  __shared__ float s_wsc[4];
  const double nvals[4] = {4194304.0, 2097152.0, 2097152.0, 4194304.0};
#pragma unroll
  for (int w = 0; w < 4; ++w) {
    double s = part[w * 256 + tid];
#pragma unroll
    for (int o = 32; o; o >>= 1) s += __shfl_xor(s, o);
    if (lane == 0) wred[w][wave] = s;
  }
  __syncthreads();
  if (tid < 4) {
    double s = (wred[tid][0] + wred[tid][1]) + (wred[tid][2] + wred[tid][3]);
    float v = fmaxf((float)(s / nvals[tid]), 1e-5f);
    s_wsc[tid] = v;
    if (blockIdx.x == 0) wsc[tid] = v;
  }
  __syncthreads();
  float inv0 = 1.f / s_wsc[0], inv1 = 1.f / s_wsc[1];
  float inv2 = 1.f / s_wsc[2], inv3 = 1.f / s_wsc[3];

  const int NQ = 3145728;
  for (int qi = blockIdx.x * 256 + tid; qi < NQ; qi += gridDim.x * 256) {
    const float* src; signed char* dst; float inv; int off;
    if (qi < 1048576)      { src = wq; dst = wqk;           off = qi;           inv = inv0; }
    else if (qi < 1572864) { src = wk; dst = wqk + 4194304; off = qi - 1048576; inv = inv1; }
    else if (qi < 2097152) { src = wv; dst = wvt;           off = qi - 1572864; inv = inv2; }
    else                   { src = wo; dst = wot;           off = qi - 2097152; inv = inv3; }
    float4 v = ((const float4*)src)[off];
    unsigned int u = 0;
    float vv[4] = {v.x, v.y, v.z, v.w};
#pragma unroll
    for (int j = 0; j < 4; ++j) {
      int q = (int)fminf(fmaxf(rintf(vv[j] * inv), -1.f), 1.f);
      u |= (unsigned int)(q & 255) << (8 * j);
    }
    ((unsigned int*)dst)[off] = u;
  }
}

// ---------------------------------------------------------------------------
// K4: i8 MFMA NT-GEMM, 128x128 tile, BK=64. 3-buffer LDS pipeline with
// counted s_waitcnt vmcnt(4) (2 tiles in flight; never drains to 0 in the
// steady-state loop), raw s_barrier, setprio around MFMA cluster.
// which==0: 512 blocks = 384 QK tiles (fused rmsnorm+rope -> fp16 qf/kf) +
//           128 V tiles (fp16 transposed vt)
// which==1: 256 blocks, O projection (f32 out, scale wsc[3])
// ---------------------------------------------------------------------------
__global__ __launch_bounds__(256) void k_gemm_i8(const signed char* __restrict__ A0,
                                                 const signed char* __restrict__ B0,
                                                 const signed char* __restrict__ B1,
                                                 int which,
                                                 float* __restrict__ d0,
                                                 unsigned short* __restrict__ dh,
                                                 const float* __restrict__ asx,
                                                 const float* __restrict__ wsc,
                                                 const float* __restrict__ qn,
                                                 const float* __restrict__ kn,
                                                 const float* __restrict__ cs,
                                                 const float* __restrict__ sn,
                                                 unsigned short* __restrict__ qf,
                                                 unsigned short* __restrict__ kf) {
  const int K = HH;
  __shared__ signed char As[3][8192];   // [buf][128][64] source-swizzled rows
  __shared__ signed char Bs[3][8192];
  int tid = threadIdx.x;
  int wave = tid >> 6, lane = tid & 63, l15 = lane & 15, g = lane >> 4;
  int wm = wave >> 1, wn = wave & 1;

  const signed char *Ap, *Bp;
  int bm, bn, mode;
  if (which == 0) {
    int gid = (blockIdx.x & 7) * 64 + (blockIdx.x >> 3);   // XCD chunk, 512 blocks
    if (gid < 384) { mode = 0; bm = (gid / 24) * 128; bn = (gid % 24) * 128; Ap = A0; Bp = B0; }
    else { mode = 1; int vid = gid - 384; bm = (vid >> 4) * 128; bn = (vid & 15) * 128; Ap = B1; Bp = A0; }
  } else {
    int gid = (blockIdx.x & 7) * 32 + (blockIdx.x >> 3);   // 256 blocks
    mode = 2; bm = (gid >> 4) * 128; bn = (gid & 15) * 128; Ap = A0; Bp = B0;
  }

  // GSTAGE: exactly 4 VMEM ops per thread (2 A + 2 B chunks of 16 B)
#define GSTAGE(K0, BUF)                                                               \
  {                                                                                   \
    _Pragma("unroll")                                                                 \
    for (int r = 0; r < 2; ++r) {                                                     \
      int c = r * 256 + tid;                                                          \
      int row = c >> 2;                                                               \
      int kk2 = ((c & 3) << 4) ^ ((row & 3) << 4);                                    \
      GLD_LDS16(Ap + (size_t)(bm + row) * K + (K0) + kk2, As[BUF] + c * 16);          \
      GLD_LDS16(Bp + (size_t)(bn + row) * K + (K0) + kk2, Bs[BUF] + c * 16);          \
    }                                                                                 \
  }

  int4v acc[4][4] = {};
  // prologue: tiles 0,1 staged; wait only tile 0 (4 loads of tile 1 in flight)
  GSTAGE(0, 0);
  GSTAGE(64, 1);
  asm volatile("s_waitcnt vmcnt(4)" ::: "memory");
  __builtin_amdgcn_s_barrier();
  __builtin_amdgcn_sched_barrier(0);

  int cur = 0, nxt = 1, nx2 = 2;
  for (int k0 = 0; k0 < K; k0 += 64) {
    bool more = (k0 + 128 < K);
    if (more) GSTAGE(k0 + 128, nx2);          // 2-ahead into third buffer
    int4v af[4], bf[4];
#pragma unroll
    for (int i = 0; i < 4; ++i) {
      int ra = wm * 64 + i * 16 + l15;
      af[i] = *(const int4v*)&As[cur][ra * 64 + ((g * 16) ^ ((ra & 3) << 4))];
      int rb = (mode == 0) ? (wn * 32 + (i & 1) * 16 + (i >> 1) * 64 + l15)
                           : (wn * 64 + i * 16 + l15);
      bf[i] = *(const int4v*)&Bs[cur][rb * 64 + ((g * 16) ^ ((rb & 3) << 4))];
    }
    __builtin_amdgcn_s_setprio(1);
#pragma unroll
    for (int mi = 0; mi < 4; ++mi)
#pragma unroll
      for (int ni = 0; ni < 4; ++ni)
        acc[mi][ni] = __builtin_amdgcn_mfma_i32_16x16x64_i8(af[mi], bf[ni], acc[mi][ni], 0, 0, 0);
    __builtin_amdgcn_s_setprio(0);
    // counted barrier: tile k0+64 guaranteed complete, tile k0+128 in flight
    if (more) { asm volatile("s_waitcnt vmcnt(4)" ::: "memory"); }
    else      { asm volatile("s_waitcnt vmcnt(0)" ::: "memory"); }
    __builtin_amdgcn_s_barrier();
    __builtin_amdgcn_sched_barrier(0);
    int t0 = cur; cur = nxt; nxt = nx2; nx2 = t0;
  }
#undef GSTAGE

  if (mode == 0) {
    // fused rmsnorm + rope epilogue -> single fp16
    bool isq = (bn < 2048);
    int hh = isq ? (bn >> 7) : ((bn - 2048) >> 7);
    float wN = isq ? wsc[0] : wsc[1];
    float ps = isq ? 0.12751743075f : 1.0f;   // (1/sqrt(128))*log2(e) for q
    const float* nw = isq ? qn : kn;
    unsigned short* oh = isq ? qf : kf;
    int nhp = isq ? NHQ : NKVH;
    float* S = (float*)&As[0][0];        // reuse LDS: [2][128] f32
    __syncthreads();                     // all waves past final loop barrier
#pragma unroll
    for (int mi = 0; mi < 4; ++mi) {
#pragma unroll
      for (int rr = 0; rr < 4; ++rr) {
        int tok = bm + wm * 64 + mi * 16 + 4 * g + rr;
        float rs = asx[tok] * wN;
        float ssum = 0.f;
#pragma unroll
        for (int ni = 0; ni < 4; ++ni) {
          float v = (float)acc[mi][ni][rr] * rs;
          ssum += v * v;
        }
        ssum += __shfl_xor(ssum, 1); ssum += __shfl_xor(ssum, 2);
        ssum += __shfl_xor(ssum, 4); ssum += __shfl_xor(ssum, 8);
        if (l15 == 0) S[wn * 128 + wm * 64 + mi * 16 + 4 * g + rr] = ssum;
      }
    }
    __syncthreads();
#pragma unroll
    for (int mi = 0; mi < 4; ++mi) {
#pragma unroll
      for (int rr = 0; rr < 4; ++rr) {
        int rloc = wm * 64 + mi * 16 + 4 * g + rr;
        int tok = bm + rloc;
        float rs = asx[tok] * wN;
        float inv = rsqrtf((S[rloc] + S[128 + rloc]) * (1.f / 128.f) + 1e-6f);
        int s = tok & (SEQ - 1);
        float nv[4];
#pragma unroll
        for (int ni = 0; ni < 4; ++ni) {
          int d = wn * 32 + (ni & 1) * 16 + (ni >> 1) * 64 + l15;
          nv[ni] = nw[d] * ((float)acc[mi][ni][rr] * rs) * inv;
        }
#pragma unroll
        for (int ni = 0; ni < 4; ++ni) {
          int d = wn * 32 + (ni & 1) * 16 + (ni >> 1) * 64 + l15;
          float oo = nv[ni ^ 2];
          float rh = (ni < 2) ? -oo : oo;
          float res = (nv[ni] * cs[s * 128 + d] + rh * sn[s * 128 + d]) * ps;
          size_t oi = ((size_t)tok * nhp + hh) * 128 + d;
          oh[oi] = f2h(res);
        }
      }
    }
  } else if (mode == 2) {
#pragma unroll
    for (int mi = 0; mi < 4; ++mi) {
#pragma unroll
      for (int rr = 0; rr < 4; ++rr) {
        int crow = bm + wm * 64 + mi * 16 + 4 * g + rr;
        float rs = asx[crow] * wsc[3];
#pragma unroll
        for (int ni = 0; ni < 4; ++ni) {
          int ccol = bn + wn * 64 + ni * 16 + l15;
          d0[(size_t)crow * 2048 + ccol] = (float)acc[mi][ni][rr] * rs;
        }
      }
    }
  } else {   // mode 1: V fp16 transposed (crow=feature, ccol=token)
    float w2 = wsc[2];
#pragma unroll
    for (int mi = 0; mi < 4; ++mi) {
#pragma unroll
      for (int rr = 0; rr < 4; ++rr) {
        int crow = bm + wm * 64 + mi * 16 + 4 * g + rr;
#pragma unroll
        for (int ni = 0; ni < 4; ++ni) {
          int ccol = bn + wn * 64 + ni * 16 + l15;
          float v = (float)acc[mi][ni][rr] * asx[ccol] * w2;
          size_t ad = ((size_t)((ccol >> 10) * 1024 + crow)) * 1024 + (ccol & 1023);
          dh[ad] = f2h(v);
        }
      }
    }
  }
}

// ---------------------------------------------------------------------------
// K6: MFMA flash attention (unchanged from round 9 — static XCD-chunked
// schedule, all-fp16, exp2 softmax, per-lane defer-max, l via constant-ones
// MFMA, 3-buffer counted-vmcnt pipeline).
// ---------------------------------------------------------------------------
__global__ __launch_bounds__(256) void k_attn_mfma(const unsigned short* __restrict__ qfp,
                                                   const unsigned short* __restrict__ kfp,
                                                   const unsigned short* __restrict__ vfp,
                                                   float* __restrict__ o) {
  int chunk = blockIdx.x & 7, j = blockIdx.x >> 3;   // XCD, within-chunk
  int qt = 15 - (j >> 2);                            // heavy first in launch order
  int yy = (chunk << 2) + (j & 3);                   // 4 heads/chunk share L2
  int b = yy >> 4, h = yy & 15, kvh = h >> 1;
  int tid = threadIdx.x;
  int wave = tid >> 6, lane = tid & 63;
  int l15 = lane & 15, g = lane >> 4;
  int q0w = qt * 64 + wave * 16;
  int qglob = q0w + l15;

  __shared__ unsigned short Kf[3][4096];     // fp16 K, [ki][d] swizzled
  __shared__ unsigned short Vf[3][4096];     // fp16 V^T [d][tok] swizzled
  __shared__ unsigned short Plds[4][16][36]; // fp16 P transpose buffer

  half8 qf[4];
  {
    const unsigned short* qb = qfp + ((size_t)(b * SEQ + qglob) * NHQ + h) * HDD + g * 8;
#pragma unroll
    for (int c = 0; c < 4; ++c) qf[c] = s2h(*(const short8*)(qb + c * 32));
  }
  half8 vones;
#pragma unroll
  for (int c = 0; c < 8; ++c) vones[c] = (_Float16)1.0f;

#define STAGE(KV0N, BUF)                                                              \
  {                                                                                   \
    int c0 = wave * 64 + lane;                                                        \
    _Pragma("unroll")                                                                 \
    for (int tch = 0; tch < 2; ++tch) {                                               \
      int c = tch * 256 + c0;                                                         \
      int ki = c >> 4, jb = (c & 15) << 4;                                            \
      int js = jb ^ ((ki & 7) << 4);                                                  \
      size_t kbase = ((size_t)(b * SEQ + (KV0N) + ki) * NKVH + kvh) * HDD;            \
      GLD_LDS16((const char*)(kfp + kbase) + js, &Kf[BUF][c * 8]);                    \
      int d = c >> 2, jv = (c & 3) << 4;                                              \
      int jvs = jv ^ ((d & 3) << 4);                                                  \
      size_t vbase = ((size_t)(b * 1024 + kvh * 128 + d)) * SEQ + (KV0N);             \
      GLD_LDS16((const char*)(vfp + vbase) + jvs, &Vf[BUF][c * 8]);                   \
    }                                                                                 \
  }

  f32x4 acc[9] = {};                 // [0..7]=O d-tiles, [8]=l (ones-V)
  float m_run = -INFINITY;
  int nkv = 2 * qt + 2;

  STAGE(0, 0);
  STAGE(32, 1);
  asm volatile("s_waitcnt vmcnt(4) lgkmcnt(0)" ::: "memory");
  __builtin_amdgcn_s_barrier();
  __builtin_amdgcn_sched_barrier(0);

  int cur = 0, nxt = 1, nx2 = 2;
  for (int kv = 0; kv < nkv; ++kv) {
    int kv0 = kv * 32;
    bool more = (kv + 2 < nkv);
    if (more) STAGE(kv0 + 64, nx2);          // 2-ahead into third buffer
    bool active = (kv0 <= q0w + 15);
    if (active) {
      const char* Kb = (const char*)&Kf[cur][0];
      const char* Vb = (const char*)&Vf[cur][0];
      // ---- QK^T (fp16, scores in log2 units) ----
      float sc[2][4];
      __builtin_amdgcn_s_setprio(1);
#pragma unroll
      for (int t = 0; t < 2; ++t) {
        int row = 16 * t + l15;
        int rbyte = row * 256, sw = (row & 7) << 4;
        f32x4 s = {0.f, 0.f, 0.f, 0.f};
#pragma unroll
        for (int c = 0; c < 4; ++c) {
          int off = rbyte + ((c * 64 + g * 16) ^ sw);
          half8 kf8 = s2h(*(const short8*)(Kb + off));
          s = __builtin_amdgcn_mfma_f32_16x16x32_f16(kf8, qf[c], s, 0, 0, 0);
        }
#pragma unroll
        for (int r = 0; r < 4; ++r) sc[t][r] = s[r];
      }
      __builtin_amdgcn_s_setprio(0);
      if (kv0 + 31 > q0w) {
#pragma unroll
        for (int t = 0; t < 2; ++t)
#pragma unroll
          for (int r = 0; r < 4; ++r)
            if (kv0 + 16 * t + 4 * g + r > qglob) sc[t][r] = -INFINITY;
      }
      // ---- online softmax (exp2; defer-max, per-lane check) ----
      float pmax = -INFINITY;
#pragma unroll
      for (int t = 0; t < 2; ++t)
#pragma unroll
        for (int r = 0; r < 4; ++r) pmax = fmaxf(pmax, sc[t][r]);
      if (!__all(pmax <= m_run + 10.f)) {
        pmax = fmaxf(pmax, __shfl_xor(pmax, 16));
        pmax = fmaxf(pmax, __shfl_xor(pmax, 32));
        float mnew = fmaxf(m_run, pmax);
        float corr = exp2f(m_run - mnew);
        m_run = mnew;
        float corro[4];
#pragma unroll
        for (int r = 0; r < 4; ++r) corro[r] = __shfl(corr, 4 * g + r);
#pragma unroll
        for (int dt = 0; dt < 9; ++dt)
#pragma unroll
          for (int r = 0; r < 4; ++r) acc[dt][r] *= corro[r];
      }
      unsigned short ph[2][4];
#pragma unroll
      for (int t = 0; t < 2; ++t)
#pragma unroll
        for (int r = 0; r < 4; ++r)
          ph[t][r] = f2h(exp2f(sc[t][r] - m_run));
      // ---- P transpose through per-wave LDS (fp16) ----
      ushort4 wh;
#pragma unroll
      for (int t = 0; t < 2; ++t) {
        wh.x = ph[t][0]; wh.y = ph[t][1]; wh.z = ph[t][2]; wh.w = ph[t][3];
        *(ushort4*)&Plds[wave][l15][16 * t + 4 * g] = wh;
      }
      half8 pa = s2h(*(const short8*)&Plds[wave][l15][8 * g]);
      // ---- PV (fp16) + l via constant-ones MFMA ----
      __builtin_amdgcn_s_setprio(1);
#pragma unroll
      for (int dt = 0; dt < 8; ++dt) {
        int d = dt * 16 + l15;
        int off = d * 64 + ((g * 16) ^ ((d & 3) << 4));
        half8 vf8 = s2h(*(const short8*)(Vb + off));
        acc[dt] = __builtin_amdgcn_mfma_f32_16x16x32_f16(pa, vf8, acc[dt], 0, 0, 0);
      }
      acc[8] = __builtin_amdgcn_mfma_f32_16x16x32_f16(pa, vones, acc[8], 0, 0, 0);
      __builtin_amdgcn_s_setprio(0);
    }
    if (more) { asm volatile("s_waitcnt vmcnt(4)" ::: "memory"); }
    else      { asm volatile("s_waitcnt vmcnt(0)" ::: "memory"); }
    __builtin_amdgcn_s_barrier();
    __builtin_amdgcn_sched_barrier(0);
    int t0 = cur; cur = nxt; nxt = nx2; nx2 = t0;
  }
#undef STAGE

  float linv[4];
#pragma unroll
  for (int r = 0; r < 4; ++r) linv[r] = 1.f / acc[8][r];
#pragma unroll
  for (int r = 0; r < 4; ++r) {
    size_t orow = ((size_t)(b * SEQ + q0w + 4 * g + r) * NHQ + h) * HDD + l15;
#pragma unroll
    for (int dt = 0; dt < 8; ++dt)
      o[orow + dt * 16] = acc[dt][r] * linv[r];
  }
}

// ---------------------------------------------------------------------------
extern "C" void kernel_launch(void* const* d_in, const int* in_sizes, int n_in,
                              void* d_out, int out_size, void* d_ws, size_t ws_size,
                              hipStream_t stream) {
  const float* x  = (const float*)d_in[0];
  const float* cs = (const float*)d_in[1];
  const float* sn = (const float*)d_in[2];
  const float* wq = (const float*)d_in[3];
  const float* wk = (const float*)d_in[4];
  const float* wv = (const float*)d_in[5];
  const float* wo = (const float*)d_in[6];
  const float* qn = (const float*)d_in[7];
  const float* kn = (const float*)d_in[8];
  float* out = (float*)d_out;
  char* ws = (char*)d_ws;

  const size_t MB = 1024 * 1024;
  size_t o_xq  = 0;            // 4 MB  int8 xq
  size_t o_wqk = 4  * MB;      // 6 MB  [3072][2048] i8
  size_t o_wvt = 10 * MB;      // 2 MB  [1024][2048] i8
  size_t o_wot = 12 * MB;      // 4 MB  [2048][2048] i8
  size_t o_vt  = 16 * MB;      // 4 MB  fp16 V transposed
  size_t o_qf  = 20 * MB;      // 8 MB  fp16 q (rope'd, log2e/sqrt(128) folded)
  size_t o_kf  = 28 * MB;      // 4 MB  fp16 k (rope'd)
  size_t o_ao  = 32 * MB;      // 16 MB f32 attn out
  size_t o_aq  = 48 * MB;      // 4 MB  int8 requant
  size_t o_as  = 52 * MB;
  size_t o_as2 = o_as  + 8192;
  size_t o_prt = o_as2 + 8192;
  size_t o_wsc = o_prt + 8192;

  signed char* xq  = (signed char*)(ws + o_xq);
  signed char* wqk = (signed char*)(ws + o_wqk);
  signed char* wvt = (signed char*)(ws + o_wvt);
  signed char* wot = (signed char*)(ws + o_wot);
  unsigned short* vt = (unsigned short*)(ws + o_vt);
  unsigned short* qf = (unsigned short*)(ws + o_qf);
  unsigned short* kf = (unsigned short*)(ws + o_kf);
  float* ao = (float*)(ws + o_ao);
  signed char* aq = (signed char*)(ws + o_aq);
  float* asx = (float*)(ws + o_as);
  float* as2 = (float*)(ws + o_as2);
  double* prt = (double*)(ws + o_prt);
  float* wsc = (float*)(ws + o_wsc);

  // 1) activation quant of x -> int8
  k_actquant<<<TT, 256, 0, stream>>>(x, xq, asx);

  // 2) weight scale partials
  k_absum_all<<<dim3(256, 4), 256, 0, stream>>>(wq, wk, wv, wo, prt);

  // 3) ternary weight quant -> int8 (scales recomputed per-block; block 0
  //    publishes wsc)
  k_wquant_all<<<2048, 256, 0, stream>>>(wq, wk, wv, wo, wqk, wvt, wot, prt, wsc);

  // 4) fused QKV projection + rmsnorm/rope epilogue (pipelined)
  k_gemm_i8<<<512, 256, 0, stream>>>(xq, wqk, wvt, 0, nullptr, vt, asx, wsc,
                                     qn, kn, cs, sn, qf, kf);

  // 5) MFMA flash attention
  k_attn_mfma<<<512, 256, 0, stream>>>(qf, kf, vt, ao);

  // 6) re-quant + output projection (pipelined)
  k_actquant<<<TT, 256, 0, stream>>>(ao, aq, as2);
  k_gemm_i8<<<256, 256, 0, stream>>>(aq, wot, nullptr, 1, out, nullptr, as2, wsc,
                                     nullptr, nullptr, nullptr, nullptr,
                                     nullptr, nullptr);
}

// Round 11
// 134.162 us; speedup vs baseline: 1.1021x; 1.0298x over previous
//
#include <hip/hip_runtime.h>
#include <hip/hip_bf16.h>

#define TT   2048   // B*S tokens
#define HH   2048   // hidden dim
#define SEQ  1024
#define NHQ  16
#define NKVH 8
#define HDD  128

typedef __attribute__((ext_vector_type(8))) short short8;
typedef __attribute__((ext_vector_type(4))) float f32x4;
typedef __attribute__((ext_vector_type(4))) int int4v;
typedef _Float16 half8 __attribute__((ext_vector_type(8)));

static __device__ __forceinline__ unsigned short f2h(float f) {
  union { _Float16 h; unsigned short u; } c;
  c.h = (_Float16)f;
  return c.u;
}
static __device__ __forceinline__ half8 s2h(short8 v) {
  union { short8 s; half8 h; } c;
  c.s = v;
  return c.h;
}

#define GLD_LDS16(gp, lp)                                                        \
  __builtin_amdgcn_global_load_lds(                                              \
      (const __attribute__((address_space(1))) void*)(const void*)(gp),          \
      (__attribute__((address_space(3))) void*)(void*)(lp), 16, 0, 0)

// ---------------------------------------------------------------------------
// K1: fused act_quant(x) + weight |w| partial sums, one dispatch.
// blocks 0..2047: per-row act quant of x. blocks 2048..3071: f64 absum
// partials (identical math/order to the old k_absum_all).
// ---------------------------------------------------------------------------
__global__ __launch_bounds__(256) void k_quant_stats(const float* __restrict__ x,
                                                     signed char* __restrict__ xq,
                                                     float* __restrict__ as_inv,
                                                     const float* __restrict__ wq,
                                                     const float* __restrict__ wk,
                                                     const float* __restrict__ wv,
                                                     const float* __restrict__ wo,
                                                     double* __restrict__ part) {
  int tid = threadIdx.x;
  int wave = tid >> 6, lane = tid & 63;
  __shared__ double redd[256];
  __shared__ float wred[4];

  if (blockIdx.x < 2048) {
    int row = blockIdx.x;
    const float4* xr4 = (const float4*)(x + (size_t)row * HH);
    float4 a = xr4[tid * 2], b = xr4[tid * 2 + 1];
    float am = fmaxf(fmaxf(fmaxf(fabsf(a.x), fabsf(a.y)), fmaxf(fabsf(a.z), fabsf(a.w))),
                     fmaxf(fmaxf(fabsf(b.x), fabsf(b.y)), fmaxf(fabsf(b.z), fabsf(b.w))));
#pragma unroll
    for (int o = 32; o; o >>= 1) am = fmaxf(am, __shfl_xor(am, o));
    if (lane == 0) wred[wave] = am;
    __syncthreads();
    am = fmaxf(fmaxf(wred[0], wred[1]), fmaxf(wred[2], wred[3]));
    am = fmaxf(am, 1e-5f);
    if (tid == 0) as_inv[row] = am / 127.f;
    float scale = 127.f / am;
    float vals[8] = {a.x, a.y, a.z, a.w, b.x, b.y, b.z, b.w};
    unsigned int u0 = 0, u1 = 0;
#pragma unroll
    for (int j = 0; j < 4; ++j) {
      int q = (int)fminf(fmaxf(rintf(vals[j] * scale), -128.f), 127.f);
      u0 |= (unsigned int)(q & 255) << (8 * j);
    }
#pragma unroll
    for (int j = 0; j < 4; ++j) {
      int q = (int)fminf(fmaxf(rintf(vals[4 + j] * scale), -128.f), 127.f);
      u1 |= (unsigned int)(q & 255) << (8 * j);
    }
    uint2 uu; uu.x = u0; uu.y = u1;
    ((uint2*)(xq + (size_t)row * HH))[tid] = uu;
  } else {
    int idx = blockIdx.x - 2048;
    int wid = idx >> 8, sub = idx & 255;
    const float* w = (wid == 0) ? wq : (wid == 1) ? wk : (wid == 2) ? wv : wo;
    int nq = ((wid == 0 || wid == 3) ? 4194304 : 2097152) >> 2;
    double s = 0.0;
    for (int i = sub * 256 + tid; i < nq; i += 256 * 256) {
      float4 v = ((const float4*)w)[i];
      s += (double)fabsf(v.x) + (double)fabsf(v.y) + (double)fabsf(v.z) + (double)fabsf(v.w);
    }
    redd[tid] = s;
    __syncthreads();
    for (int st = 128; st > 0; st >>= 1) {
      if (tid < st) redd[tid] += redd[tid + st];
      __syncthreads();
    }
    if (tid == 0) part[wid * 256 + sub] = redd[0];
  }
}

// ---------------------------------------------------------------------------
// K3: ternary weight quant -> int8 for wq,wk,wv (wot is quantized inside the
// QKV GEMM dispatch). Each block recomputes the 4 scales from the f64
// partials (deterministic); block 0 publishes wsc.
// ---------------------------------------------------------------------------
__global__ __launch_bounds__(256) void k_wquant_all(const float* __restrict__ wq,
                                                    const float* __restrict__ wk,
                                                    const float* __restrict__ wv,
                                                    signed char* __restrict__ wqk,
                                                    signed char* __restrict__ wvt,
                                                    const double* __restrict__ part,
                                                    float* __restrict__ wsc) {
  int tid = threadIdx.x;
  int wave = tid >> 6, lane = tid & 63;
  __shared__ double wred[4][4];
  __shared__ float s_wsc[4];
  const double nvals[4] = {4194304.0, 2097152.0, 2097152.0, 4194304.0};
#pragma unroll
  for (int w = 0; w < 4; ++w) {
    double s = part[w * 256 + tid];
#pragma unroll
    for (int o = 32; o; o >>= 1) s += __shfl_xor(s, o);
    if (lane == 0) wred[w][wave] = s;
  }
  __syncthreads();
  if (tid < 4) {
    double s = (wred[tid][0] + wred[tid][1]) + (wred[tid][2] + wred[tid][3]);
    float v = fmaxf((float)(s / nvals[tid]), 1e-5f);
    s_wsc[tid] = v;
    if (blockIdx.x == 0) wsc[tid] = v;
  }
  __syncthreads();
  float inv0 = 1.f / s_wsc[0], inv1 = 1.f / s_wsc[1], inv2 = 1.f / s_wsc[2];

  const int NQ = 2097152;   // wq(1048576) + wk(524288) + wv(524288) quads
  for (int qi = blockIdx.x * 256 + tid; qi < NQ; qi += gridDim.x * 256) {
    const float* src; signed char* dst; float inv; int off;
    if (qi < 1048576)      { src = wq; dst = wqk;           off = qi;           inv = inv0; }
    else if (qi < 1572864) { src = wk; dst = wqk + 4194304; off = qi - 1048576; inv = inv1; }
    else                   { src = wv; dst = wvt;           off = qi - 1572864; inv = inv2; }
    float4 v = ((const float4*)src)[off];
    unsigned int u = 0;
    float vv[4] = {v.x, v.y, v.z, v.w};
#pragma unroll
    for (int j = 0; j < 4; ++j) {
      int q = (int)fminf(fmaxf(rintf(vv[j] * inv), -1.f), 1.f);
      u |= (unsigned int)(q & 255) << (8 * j);
    }
    ((unsigned int*)dst)[off] = u;
  }
}

// ---------------------------------------------------------------------------
// K4: QKV i8 MFMA NT-GEMM (128x128, BK=64, 3-buffer counted-vmcnt pipeline)
// + hosts wot ternary quant in blocks 512..639 (wot needed only by O-GEMM).
// blocks 0..511: 384 QK tiles (fused rmsnorm+rope -> fp16 qf/kf) +
//                128 V tiles (fp16 transposed vt)
// ---------------------------------------------------------------------------
__global__ __launch_bounds__(256) void k_gemm_i8(const signed char* __restrict__ A0,
                                                 const signed char* __restrict__ B0,
                                                 const signed char* __restrict__ B1,
                                                 unsigned short* __restrict__ dh,
                                                 const float* __restrict__ asx,
                                                 const float* __restrict__ wsc,
                                                 const float* __restrict__ qn,
                                                 const float* __restrict__ kn,
                                                 const float* __restrict__ cs,
                                                 const float* __restrict__ sn,
                                                 unsigned short* __restrict__ qf,
                                                 unsigned short* __restrict__ kf,
                                                 const float* __restrict__ wo_f32,
                                                 signed char* __restrict__ wot) {
  const int K = HH;
  __shared__ signed char As[3][8192];   // [buf][128][64] source-swizzled rows
  __shared__ signed char Bs[3][8192];
  int tid = threadIdx.x;
  int wave = tid >> 6, lane = tid & 63, l15 = lane & 15, g = lane >> 4;
  int wm = wave >> 1, wn = wave & 1;

  if (blockIdx.x >= 512) {
    // ---- wot ternary quant (runs in GEMM tail slots) ----
    int bx = blockIdx.x - 512;          // 0..127
    float inv = 1.f / wsc[3];
    for (int qi = bx * 256 + tid; qi < 1048576; qi += 128 * 256) {
      float4 v = ((const float4*)wo_f32)[qi];
      unsigned int u = 0;
      float vv[4] = {v.x, v.y, v.z, v.w};
#pragma unroll
      for (int j = 0; j < 4; ++j) {
        int q = (int)fminf(fmaxf(rintf(vv[j] * inv), -1.f), 1.f);
        u |= (unsigned int)(q & 255) << (8 * j);
      }
      ((unsigned int*)wot)[qi] = u;
    }
    return;
  }

  const signed char *Ap, *Bp;
  int bm, bn, mode;
  {
    int gid = (blockIdx.x & 7) * 64 + (blockIdx.x >> 3);   // XCD chunk, 512 blocks
    if (gid < 384) { mode = 0; bm = (gid / 24) * 128; bn = (gid % 24) * 128; Ap = A0; Bp = B0; }
    else { mode = 1; int vid = gid - 384; bm = (vid >> 4) * 128; bn = (vid & 15) * 128; Ap = B1; Bp = A0; }
  }

#define GSTAGE(K0, BUF)                                                               \
  {                                                                                   \
    _Pragma("unroll")                                                                 \
    for (int r = 0; r < 2; ++r) {                                                     \
      int c = r * 256 + tid;                                                          \
      int row = c >> 2;                                                               \
      int kk2 = ((c & 3) << 4) ^ ((row & 3) << 4);                                    \
      GLD_LDS16(Ap + (size_t)(bm + row) * K + (K0) + kk2, As[BUF] + c * 16);          \
      GLD_LDS16(Bp + (size_t)(bn + row) * K + (K0) + kk2, Bs[BUF] + c * 16);          \
    }                                                                                 \
  }

  int4v acc[4][4] = {};
  GSTAGE(0, 0);
  GSTAGE(64, 1);
  asm volatile("s_waitcnt vmcnt(4)" ::: "memory");
  __builtin_amdgcn_s_barrier();
  __builtin_amdgcn_sched_barrier(0);

  int cur = 0, nxt = 1, nx2 = 2;
  for (int k0 = 0; k0 < K; k0 += 64) {
    bool more = (k0 + 128 < K);
    if (more) GSTAGE(k0 + 128, nx2);
    int4v af[4], bf[4];
#pragma unroll
    for (int i = 0; i < 4; ++i) {
      int ra = wm * 64 + i * 16 + l15;
      af[i] = *(const int4v*)&As[cur][ra * 64 + ((g * 16) ^ ((ra & 3) << 4))];
      int rb = (mode == 0) ? (wn * 32 + (i & 1) * 16 + (i >> 1) * 64 + l15)
                           : (wn * 64 + i * 16 + l15);
      bf[i] = *(const int4v*)&Bs[cur][rb * 64 + ((g * 16) ^ ((rb & 3) << 4))];
    }
    __builtin_amdgcn_s_setprio(1);
#pragma unroll
    for (int mi = 0; mi < 4; ++mi)
#pragma unroll
      for (int ni = 0; ni < 4; ++ni)
        acc[mi][ni] = __builtin_amdgcn_mfma_i32_16x16x64_i8(af[mi], bf[ni], acc[mi][ni], 0, 0, 0);
    __builtin_amdgcn_s_setprio(0);
    if (more) { asm volatile("s_waitcnt vmcnt(4)" ::: "memory"); }
    else      { asm volatile("s_waitcnt vmcnt(0)" ::: "memory"); }
    __builtin_amdgcn_s_barrier();
    __builtin_amdgcn_sched_barrier(0);
    int t0 = cur; cur = nxt; nxt = nx2; nx2 = t0;
  }
#undef GSTAGE

  if (mode == 0) {
    // fused rmsnorm + rope epilogue -> single fp16
    bool isq = (bn < 2048);
    int hh = isq ? (bn >> 7) : ((bn - 2048) >> 7);
    float wN = isq ? wsc[0] : wsc[1];
    float ps = isq ? 0.12751743075f : 1.0f;   // (1/sqrt(128))*log2(e) for q
    const float* nw = isq ? qn : kn;
    unsigned short* oh = isq ? qf : kf;
    int nhp = isq ? NHQ : NKVH;
    float* S = (float*)&As[0][0];        // reuse LDS: [2][128] f32
    __syncthreads();
#pragma unroll
    for (int mi = 0; mi < 4; ++mi) {
#pragma unroll
      for (int rr = 0; rr < 4; ++rr) {
        int tok = bm + wm * 64 + mi * 16 + 4 * g + rr;
        float rs = asx[tok] * wN;
        float ssum = 0.f;
#pragma unroll
        for (int ni = 0; ni < 4; ++ni) {
          float v = (float)acc[mi][ni][rr] * rs;
          ssum += v * v;
        }
        ssum += __shfl_xor(ssum, 1); ssum += __shfl_xor(ssum, 2);
        ssum += __shfl_xor(ssum, 4); ssum += __shfl_xor(ssum, 8);
        if (l15 == 0) S[wn * 128 + wm * 64 + mi * 16 + 4 * g + rr] = ssum;
      }
    }
    __syncthreads();
#pragma unroll
    for (int mi = 0; mi < 4; ++mi) {
#pragma unroll
      for (int rr = 0; rr < 4; ++rr) {
        int rloc = wm * 64 + mi * 16 + 4 * g + rr;
        int tok = bm + rloc;
        float rs = asx[tok] * wN;
        float inv = rsqrtf((S[rloc] + S[128 + rloc]) * (1.f / 128.f) + 1e-6f);
        int s = tok & (SEQ - 1);
        float nv[4];
#pragma unroll
        for (int ni = 0; ni < 4; ++ni) {
          int d = wn * 32 + (ni & 1) * 16 + (ni >> 1) * 64 + l15;
          nv[ni] = nw[d] * ((float)acc[mi][ni][rr] * rs) * inv;
        }
#pragma unroll
        for (int ni = 0; ni < 4; ++ni) {
          int d = wn * 32 + (ni & 1) * 16 + (ni >> 1) * 64 + l15;
          float oo = nv[ni ^ 2];
          float rh = (ni < 2) ? -oo : oo;
          float res = (nv[ni] * cs[s * 128 + d] + rh * sn[s * 128 + d]) * ps;
          size_t oi = ((size_t)tok * nhp + hh) * 128 + d;
          oh[oi] = f2h(res);
        }
      }
    }
  } else {   // mode 1: V fp16 transposed (crow=feature, ccol=token)
    float w2 = wsc[2];
#pragma unroll
    for (int mi = 0; mi < 4; ++mi) {
#pragma unroll
      for (int rr = 0; rr < 4; ++rr) {
        int crow = bm + wm * 64 + mi * 16 + 4 * g + rr;
#pragma unroll
        for (int ni = 0; ni < 4; ++ni) {
          int ccol = bn + wn * 64 + ni * 16 + l15;
          float v = (float)acc[mi][ni][rr] * asx[ccol] * w2;
          size_t ad = ((size_t)((ccol >> 10) * 1024 + crow)) * 1024 + (ccol & 1023);
          dh[ad] = f2h(v);
        }
      }
    }
  }
}

// ---------------------------------------------------------------------------
// K4b: O projection, 128x64 tiles -> 512 blocks (2/CU), 3-buffer pipeline
// with counted vmcnt(3) (OSTAGE = 3 VMEM ops/thread).
// ---------------------------------------------------------------------------
__global__ __launch_bounds__(256) void k_gemm_o(const signed char* __restrict__ A,
                                                const signed char* __restrict__ B,
                                                float* __restrict__ d0,
                                                const float* __restrict__ asx,
                                                const float* __restrict__ wsc) {
  const int K = HH;
  __shared__ signed char As[3][8192];   // [buf][128][64]
  __shared__ signed char Bs[3][4096];   // [buf][64][64]
  int tid = threadIdx.x;
  int wave = tid >> 6, lane = tid & 63, l15 = lane & 15, g = lane >> 4;
  int gid = (blockIdx.x & 7) * 64 + (blockIdx.x >> 3);
  int bm = (gid >> 5) * 128, bn = (gid & 31) * 64;

#define OSTAGE(K0, BUF)                                                               \
  {                                                                                   \
    _Pragma("unroll")                                                                 \
    for (int r = 0; r < 2; ++r) {                                                     \
      int c = r * 256 + tid;                                                          \
      int row = c >> 2;                                                               \
      int kk2 = ((c & 3) << 4) ^ ((row & 3) << 4);                                    \
      GLD_LDS16(A + (size_t)(bm + row) * K + (K0) + kk2, As[BUF] + c * 16);           \
    }                                                                                 \
    {                                                                                 \
      int row = tid >> 2;                                                             \
      int kk2 = ((tid & 3) << 4) ^ ((row & 3) << 4);                                  \
      GLD_LDS16(B + (size_t)(bn + row) * K + (K0) + kk2, Bs[BUF] + tid * 16);         \
    }                                                                                 \
  }

  int4v acc[2][4] = {};
  OSTAGE(0, 0);
  OSTAGE(64, 1);
  asm volatile("s_waitcnt vmcnt(3)" ::: "memory");
  __builtin_amdgcn_s_barrier();
  __builtin_amdgcn_sched_barrier(0);

  int cur = 0, nxt = 1, nx2 = 2;
  for (int k0 = 0; k0 < K; k0 += 64) {
    bool more = (k0 + 128 < K);
    if (more) OSTAGE(k0 + 128, nx2);
    int4v af[2], bf[4];
#pragma unroll
    for (int i = 0; i < 2; ++i) {
      int ra = wave * 32 + i * 16 + l15;
      af[i] = *(const int4v*)&As[cur][ra * 64 + ((g * 16) ^ ((ra & 3) << 4))];
    }
#pragma unroll
    for (int n = 0; n < 4; ++n) {
      int rb = n * 16 + l15;
      bf[n] = *(const int4v*)&Bs[cur][rb * 64 + ((g * 16) ^ ((rb & 3) << 4))];
    }
    __builtin_amdgcn_s_setprio(1);
#pragma unroll
    for (int mi = 0; mi < 2; ++mi)
#pragma unroll
      for (int ni = 0; ni < 4; ++ni)
        acc[mi][ni] = __builtin_amdgcn_mfma_i32_16x16x64_i8(af[mi], bf[ni], acc[mi][ni], 0, 0, 0);
    __builtin_amdgcn_s_setprio(0);
    if (more) { asm volatile("s_waitcnt vmcnt(3)" ::: "memory"); }
    else      { asm volatile("s_waitcnt vmcnt(0)" ::: "memory"); }
    __builtin_amdgcn_s_barrier();
    __builtin_amdgcn_sched_barrier(0);
    int t0 = cur; cur = nxt; nxt = nx2; nx2 = t0;
  }
#undef OSTAGE

  float w3 = wsc[3];
#pragma unroll
  for (int mi = 0; mi < 2; ++mi) {
#pragma unroll
    for (int rr = 0; rr < 4; ++rr) {
      int crow = bm + wave * 32 + mi * 16 + 4 * g + rr;
      float rs = asx[crow] * w3;
#pragma unroll
      for (int ni = 0; ni < 4; ++ni) {
        int ccol = bn + ni * 16 + l15;
        d0[(size_t)crow * 2048 + ccol] = (float)acc[mi][ni][rr] * rs;
      }
    }
  }
}

// ---------------------------------------------------------------------------
// K5: per-row act_quant for requant of attn out (unchanged)
// ---------------------------------------------------------------------------
__global__ __launch_bounds__(256) void k_actquant(const float* __restrict__ x,
                                                  signed char* __restrict__ xq,
                                                  float* __restrict__ as_inv) {
  int row = blockIdx.x, tid = threadIdx.x;
  int wave = tid >> 6, lane = tid & 63;
  const float4* xr4 = (const float4*)(x + (size_t)row * HH);
  float4 a = xr4[tid * 2], b = xr4[tid * 2 + 1];
  float am = fmaxf(fmaxf(fmaxf(fabsf(a.x), fabsf(a.y)), fmaxf(fabsf(a.z), fabsf(a.w))),
                   fmaxf(fmaxf(fabsf(b.x), fabsf(b.y)), fmaxf(fabsf(b.z), fabsf(b.w))));
#pragma unroll
  for (int o = 32; o; o >>= 1) am = fmaxf(am, __shfl_xor(am, o));
  __shared__ float wred[4];
  if (lane == 0) wred[wave] = am;
  __syncthreads();
  am = fmaxf(fmaxf(wred[0], wred[1]), fmaxf(wred[2], wred[3]));
  am = fmaxf(am, 1e-5f);
  if (tid == 0) as_inv[row] = am / 127.f;
  float scale = 127.f / am;
  float vals[8] = {a.x, a.y, a.z, a.w, b.x, b.y, b.z, b.w};
  unsigned int u0 = 0, u1 = 0;
#pragma unroll
  for (int j = 0; j < 4; ++j) {
    int q = (int)fminf(fmaxf(rintf(vals[j] * scale), -128.f), 127.f);
    u0 |= (unsigned int)(q & 255) << (8 * j);
  }
#pragma unroll
  for (int j = 0; j < 4; ++j) {
    int q = (int)fminf(fmaxf(rintf(vals[4 + j] * scale), -128.f), 127.f);
    u1 |= (unsigned int)(q & 255) << (8 * j);
  }
  uint2 uu; uu.x = u0; uu.y = u1;
  ((uint2*)(xq + (size_t)row * HH))[tid] = uu;
}

// ---------------------------------------------------------------------------
// K6: MFMA flash attention. Balanced CU pairing: first 32 blocks/XCD are the
// heavy half (qt 15..8), second 32 the light half in matching CU order ->
// with 2 blocks/CU every CU gets qt=a and qt=15-a (34 tile-equivalents).
// All-fp16, exp2 softmax, per-lane defer-max, l via constant-ones MFMA,
// 3-buffer counted-vmcnt pipeline.
// ---------------------------------------------------------------------------
__global__ __launch_bounds__(256) void k_attn_mfma(const unsigned short* __restrict__ qfp,
                                                   const unsigned short* __restrict__ kfp,
                                                   const unsigned short* __restrict__ vfp,
                                                   float* __restrict__ o) {
  int chunk = blockIdx.x & 7, j = blockIdx.x >> 3;   // XCD, within-chunk
  int qt, yyi;
  if (j < 32) { qt = 15 - (j >> 2); yyi = j & 3; }          // heavy half first
  else        { qt = (j - 32) >> 2; yyi = (j - 32) & 3; }   // paired light half
  int yy = (chunk << 2) + yyi;
  int b = yy >> 4, h = yy & 15, kvh = h >> 1;
  int tid = threadIdx.x;
  int wave = tid >> 6, lane = tid & 63;
  int l15 = lane & 15, g = lane >> 4;
  int q0w = qt * 64 + wave * 16;
  int qglob = q0w + l15;

  __shared__ unsigned short Kf[3][4096];     // fp16 K, [ki][d] swizzled
  __shared__ unsigned short Vf[3][4096];     // fp16 V^T [d][tok] swizzled
  __shared__ unsigned short Plds[4][16][36]; // fp16 P transpose buffer

  half8 qf[4];
  {
    const unsigned short* qb = qfp + ((size_t)(b * SEQ + qglob) * NHQ + h) * HDD + g * 8;
#pragma unroll
    for (int c = 0; c < 4; ++c) qf[c] = s2h(*(const short8*)(qb + c * 32));
  }
  half8 vones;
#pragma unroll
  for (int c = 0; c < 8; ++c) vones[c] = (_Float16)1.0f;

#define STAGE(KV0N, BUF)                                                              \
  {                                                                                   \
    int c0 = wave * 64 + lane;                                                        \
    _Pragma("unroll")                                                                 \
    for (int tch = 0; tch < 2; ++tch) {                                               \
      int c = tch * 256 + c0;                                                         \
      int ki = c >> 4, jb = (c & 15) << 4;                                            \
      int js = jb ^ ((ki & 7) << 4);                                                  \
      size_t kbase = ((size_t)(b * SEQ + (KV0N) + ki) * NKVH + kvh) * HDD;            \
      GLD_LDS16((const char*)(kfp + kbase) + js, &Kf[BUF][c * 8]);                    \
      int d = c >> 2, jv = (c & 3) << 4;                                              \
      int jvs = jv ^ ((d & 3) << 4);                                                  \
      size_t vbase = ((size_t)(b * 1024 + kvh * 128 + d)) * SEQ + (KV0N);             \
      GLD_LDS16((const char*)(vfp + vbase) + jvs, &Vf[BUF][c * 8]);                   \
    }                                                                                 \
  }

  f32x4 acc[9] = {};                 // [0..7]=O d-tiles, [8]=l (ones-V)
  float m_run = -INFINITY;
  int nkv = 2 * qt + 2;

  STAGE(0, 0);
  STAGE(32, 1);
  asm volatile("s_waitcnt vmcnt(4) lgkmcnt(0)" ::: "memory");
  __builtin_amdgcn_s_barrier();
  __builtin_amdgcn_sched_barrier(0);

  int cur = 0, nxt = 1, nx2 = 2;
  for (int kv = 0; kv < nkv; ++kv) {
    int kv0 = kv * 32;
    bool more = (kv + 2 < nkv);
    if (more) STAGE(kv0 + 64, nx2);          // 2-ahead into third buffer
    bool active = (kv0 <= q0w + 15);
    if (active) {
      const char* Kb = (const char*)&Kf[cur][0];
      const char* Vb = (const char*)&Vf[cur][0];
      // ---- QK^T (fp16, scores in log2 units) ----
      float sc[2][4];
      __builtin_amdgcn_s_setprio(1);
#pragma unroll
      for (int t = 0; t < 2; ++t) {
        int row = 16 * t + l15;
        int rbyte = row * 256, sw = (row & 7) << 4;
        f32x4 s = {0.f, 0.f, 0.f, 0.f};
#pragma unroll
        for (int c = 0; c < 4; ++c) {
          int off = rbyte + ((c * 64 + g * 16) ^ sw);
          half8 kf8 = s2h(*(const short8*)(Kb + off));
          s = __builtin_amdgcn_mfma_f32_16x16x32_f16(kf8, qf[c], s, 0, 0, 0);
        }
#pragma unroll
        for (int r = 0; r < 4; ++r) sc[t][r] = s[r];
      }
      __builtin_amdgcn_s_setprio(0);
      if (kv0 + 31 > q0w) {
#pragma unroll
        for (int t = 0; t < 2; ++t)
#pragma unroll
          for (int r = 0; r < 4; ++r)
            if (kv0 + 16 * t + 4 * g + r > qglob) sc[t][r] = -INFINITY;
      }
      // ---- online softmax (exp2; defer-max, per-lane check) ----
      float pmax = -INFINITY;
#pragma unroll
      for (int t = 0; t < 2; ++t)
#pragma unroll
        for (int r = 0; r < 4; ++r) pmax = fmaxf(pmax, sc[t][r]);
      if (!__all(pmax <= m_run + 10.f)) {
        pmax = fmaxf(pmax, __shfl_xor(pmax, 16));
        pmax = fmaxf(pmax, __shfl_xor(pmax, 32));
        float mnew = fmaxf(m_run, pmax);
        float corr = exp2f(m_run - mnew);
        m_run = mnew;
        float corro[4];
#pragma unroll
        for (int r = 0; r < 4; ++r) corro[r] = __shfl(corr, 4 * g + r);
#pragma unroll
        for (int dt = 0; dt < 9; ++dt)
#pragma unroll
          for (int r = 0; r < 4; ++r) acc[dt][r] *= corro[r];
      }
      unsigned short ph[2][4];
#pragma unroll
      for (int t = 0; t < 2; ++t)
#pragma unroll
        for (int r = 0; r < 4; ++r)
          ph[t][r] = f2h(exp2f(sc[t][r] - m_run));
      // ---- P transpose through per-wave LDS (fp16) ----
      ushort4 wh;
#pragma unroll
      for (int t = 0; t < 2; ++t) {
        wh.x = ph[t][0]; wh.y = ph[t][1]; wh.z = ph[t][2]; wh.w = ph[t][3];
        *(ushort4*)&Plds[wave][l15][16 * t + 4 * g] = wh;
      }
      half8 pa = s2h(*(const short8*)&Plds[wave][l15][8 * g]);
      // ---- PV (fp16) + l via constant-ones MFMA ----
      __builtin_amdgcn_s_setprio(1);
#pragma unroll
      for (int dt = 0; dt < 8; ++dt) {
        int d = dt * 16 + l15;
        int off = d * 64 + ((g * 16) ^ ((d & 3) << 4));
        half8 vf8 = s2h(*(const short8*)(Vb + off));
        acc[dt] = __builtin_amdgcn_mfma_f32_16x16x32_f16(pa, vf8, acc[dt], 0, 0, 0);
      }
      acc[8] = __builtin_amdgcn_mfma_f32_16x16x32_f16(pa, vones, acc[8], 0, 0, 0);
      __builtin_amdgcn_s_setprio(0);
    }
    if (more) { asm volatile("s_waitcnt vmcnt(4)" ::: "memory"); }
    else      { asm volatile("s_waitcnt vmcnt(0)" ::: "memory"); }
    __builtin_amdgcn_s_barrier();
    __builtin_amdgcn_sched_barrier(0);
    int t0 = cur; cur = nxt; nxt = nx2; nx2 = t0;
  }
#undef STAGE

  float linv[4];
#pragma unroll
  for (int r = 0; r < 4; ++r) linv[r] = 1.f / acc[8][r];
#pragma unroll
  for (int r = 0; r < 4; ++r) {
    size_t orow = ((size_t)(b * SEQ + q0w + 4 * g + r) * NHQ + h) * HDD + l15;
#pragma unroll
    for (int dt = 0; dt < 8; ++dt)
      o[orow + dt * 16] = acc[dt][r] * linv[r];
  }
}

// ---------------------------------------------------------------------------
extern "C" void kernel_launch(void* const* d_in, const int* in_sizes, int n_in,
                              void* d_out, int out_size, void* d_ws, size_t ws_size,
                              hipStream_t stream) {
  const float* x  = (const float*)d_in[0];
  const float* cs = (const float*)d_in[1];
  const float* sn = (const float*)d_in[2];
  const float* wq = (const float*)d_in[3];
  const float* wk = (const float*)d_in[4];
  const float* wv = (const float*)d_in[5];
  const float* wo = (const float*)d_in[6];
  const float* qn = (const float*)d_in[7];
  const float* kn = (const float*)d_in[8];
  float* out = (float*)d_out;
  char* ws = (char*)d_ws;

  const size_t MB = 1024 * 1024;
  size_t o_xq  = 0;            // 4 MB  int8 xq
  size_t o_wqk = 4  * MB;      // 6 MB  [3072][2048] i8
  size_t o_wvt = 10 * MB;      // 2 MB  [1024][2048] i8
  size_t o_wot = 12 * MB;      // 4 MB  [2048][2048] i8
  size_t o_vt  = 16 * MB;      // 4 MB  fp16 V transposed
  size_t o_qf  = 20 * MB;      // 8 MB  fp16 q (rope'd, log2e/sqrt(128) folded)
  size_t o_kf  = 28 * MB;      // 4 MB  fp16 k (rope'd)
  size_t o_ao  = 32 * MB;      // 16 MB f32 attn out
  size_t o_aq  = 48 * MB;      // 4 MB  int8 requant
  size_t o_as  = 52 * MB;
  size_t o_as2 = o_as  + 8192;
  size_t o_prt = o_as2 + 8192;
  size_t o_wsc = o_prt + 8192;

  signed char* xq  = (signed char*)(ws + o_xq);
  signed char* wqk = (signed char*)(ws + o_wqk);
  signed char* wvt = (signed char*)(ws + o_wvt);
  signed char* wot = (signed char*)(ws + o_wot);
  unsigned short* vt = (unsigned short*)(ws + o_vt);
  unsigned short* qf = (unsigned short*)(ws + o_qf);
  unsigned short* kf = (unsigned short*)(ws + o_kf);
  float* ao = (float*)(ws + o_ao);
  signed char* aq = (signed char*)(ws + o_aq);
  float* asx = (float*)(ws + o_as);
  float* as2 = (float*)(ws + o_as2);
  double* prt = (double*)(ws + o_prt);
  float* wsc = (float*)(ws + o_wsc);

  // 1) act quant of x + weight |w| partials (one dispatch)
  k_quant_stats<<<3072, 256, 0, stream>>>(x, xq, asx, wq, wk, wv, wo, prt);

  // 2) ternary quant of wq/wk/wv (publishes wsc)
  k_wquant_all<<<1024, 256, 0, stream>>>(wq, wk, wv, wqk, wvt, prt, wsc);

  // 3) fused QKV projection + rmsnorm/rope epilogue + wot quant (one dispatch)
  k_gemm_i8<<<640, 256, 0, stream>>>(xq, wqk, wvt, vt, asx, wsc,
                                     qn, kn, cs, sn, qf, kf, wo, wot);

  // 4) MFMA flash attention (balanced CU pairing)
  k_attn_mfma<<<512, 256, 0, stream>>>(qf, kf, vt, ao);

  // 5) re-quant + output projection (128x64 tiles, 512 blocks)
  k_actquant<<<TT, 256, 0, stream>>>(ao, aq, as2);
  k_gemm_o<<<512, 256, 0, stream>>>(aq, wot, out, as2, wsc);
}